// Round 1
// baseline (2908.585 us; speedup 1.0000x reference)
//
#include <hip/hip_runtime.h>

// Problem constants (fixed by the reference).
#define N_NODES 50000
#define N_EDGES 800000
#define X_DIM 128
#define H_DIM 256
#define Y_DIM 128

// ---------------------------------------------------------------------------
// Kernel 1: per-row reciprocal sum  inv[i] = 1 / (sum_d x[i,d] + 1e-4)
// One wave (64 lanes) per row; float2 per lane covers 128 dims.
// ---------------------------------------------------------------------------
__global__ __launch_bounds__(256) void rowsum_inv_kernel(
    const float* __restrict__ x, float* __restrict__ inv) {
    int wave = (blockIdx.x * blockDim.x + threadIdx.x) >> 6;
    int lane = threadIdx.x & 63;
    if (wave >= N_NODES) return;
    const float2* xr = (const float2*)(x + (size_t)wave * X_DIM);
    float2 v = xr[lane];
    float s = v.x + v.y;
    #pragma unroll
    for (int off = 32; off > 0; off >>= 1) s += __shfl_down(s, off, 64);
    if (lane == 0) inv[wave] = 1.0f / (s + 1e-4f);
}

// ---------------------------------------------------------------------------
// Kernel 2: edge scatter  out[row] += scale_e * feat[col]   (D = 128)
// 32 lanes per edge, float4 gather, 4 fp32 atomics per lane.
// NORM=true folds the row-normalization of x into the edge scale.
// ---------------------------------------------------------------------------
template <bool NORM>
__global__ __launch_bounds__(256) void spmm_scatter128(
    const float* __restrict__ feat, const float* __restrict__ vals,
    const int* __restrict__ rows, const int* __restrict__ cols,
    const float* __restrict__ inv, float* __restrict__ out) {
    int t = blockIdx.x * blockDim.x + threadIdx.x;
    int e = t >> 5;
    if (e >= N_EDGES) return;
    int q = t & 31;
    int r = rows[e];
    int c = cols[e];
    float scale = vals[e];
    if (NORM) scale *= inv[c];
    float4 v = ((const float4*)(feat + (size_t)c * 128))[q];
    float* o = out + (size_t)r * 128 + q * 4;
    atomicAdd(o + 0, scale * v.x);
    atomicAdd(o + 1, scale * v.y);
    atomicAdd(o + 2, scale * v.z);
    atomicAdd(o + 3, scale * v.w);
}

// ---------------------------------------------------------------------------
// Kernel 3: h = relu(A @ W1 + b1), A:[n,128], W1:[128,256]
// Tile 32 rows x 256 cols. 256 threads: jj = tx&63 (4 cols: jj+64c),
// rg = tx>>6 (8 rows). Per k: 8 LDS broadcasts + 4 coalesced W loads + 32 FMA.
// ---------------------------------------------------------------------------
__global__ __launch_bounds__(256) void gemm1_relu(
    const float* __restrict__ A, const float* __restrict__ W,
    const float* __restrict__ bias, float* __restrict__ out, int nrows) {
    __shared__ float a_s[32 * 128];  // 16 KB
    const int tx = threadIdx.x;
    const int jj = tx & 63;
    const int rg = tx >> 6;  // rows rg*8 .. rg*8+7
    const int row0 = blockIdx.x * 32;

    {   // stage A tile: 4096 floats = 1024 float4
        const float4* src = (const float4*)A;
        float4* dst = (float4*)a_s;
        #pragma unroll
        for (int i = 0; i < 4; i++) {
            int idx = tx + i * 256;
            int rr = idx >> 5;  // 32 float4 per row
            float4 v = make_float4(0.f, 0.f, 0.f, 0.f);
            if (row0 + rr < nrows) v = src[(size_t)row0 * 32 + idx];
            dst[idx] = v;
        }
    }
    __syncthreads();

    float acc[8][4];
    #pragma unroll
    for (int r = 0; r < 8; r++)
        #pragma unroll
        for (int c = 0; c < 4; c++) acc[r][c] = 0.f;

    const float* Wj = W + jj;
    #pragma unroll 4
    for (int k = 0; k < 128; k++) {
        float w0 = Wj[k * 256 + 0];
        float w1 = Wj[k * 256 + 64];
        float w2 = Wj[k * 256 + 128];
        float w3 = Wj[k * 256 + 192];
        #pragma unroll
        for (int r = 0; r < 8; r++) {
            float a = a_s[(rg * 8 + r) * 128 + k];
            acc[r][0] += a * w0;
            acc[r][1] += a * w1;
            acc[r][2] += a * w2;
            acc[r][3] += a * w3;
        }
    }

    float b[4];
    #pragma unroll
    for (int c = 0; c < 4; c++) b[c] = bias[jj + c * 64];
    #pragma unroll
    for (int r = 0; r < 8; r++) {
        int row = row0 + rg * 8 + r;
        if (row < nrows) {
            float* o = out + (size_t)row * 256 + jj;
            #pragma unroll
            for (int c = 0; c < 4; c++) {
                float v = acc[r][c] + b[c];
                o[c * 64] = v > 0.f ? v : 0.f;
            }
        }
    }
}

// ---------------------------------------------------------------------------
// Kernel 4: hw = h @ W2, h:[n,256], W2:[256,128] (no bias here)
// Tile 64 rows x 128 cols. 256 threads: jj = tx&31 (4 cols: jj+32c),
// rg = tx>>5 (8 rows).
// ---------------------------------------------------------------------------
__global__ __launch_bounds__(256) void gemm2_plain(
    const float* __restrict__ A, const float* __restrict__ W,
    float* __restrict__ out, int nrows) {
    __shared__ float a_s[64 * 256];  // 64 KB
    const int tx = threadIdx.x;
    const int jj = tx & 31;
    const int rg = tx >> 5;  // rows rg*8 .. rg*8+7
    const int row0 = blockIdx.x * 64;

    {   // stage A tile: 16384 floats = 4096 float4
        const float4* src = (const float4*)A;
        float4* dst = (float4*)a_s;
        #pragma unroll
        for (int i = 0; i < 16; i++) {
            int idx = tx + i * 256;
            int rr = idx >> 6;  // 64 float4 per row
            float4 v = make_float4(0.f, 0.f, 0.f, 0.f);
            if (row0 + rr < nrows) v = src[(size_t)row0 * 64 + idx];
            dst[idx] = v;
        }
    }
    __syncthreads();

    float acc[8][4];
    #pragma unroll
    for (int r = 0; r < 8; r++)
        #pragma unroll
        for (int c = 0; c < 4; c++) acc[r][c] = 0.f;

    const float* Wj = W + jj;
    #pragma unroll 4
    for (int k = 0; k < 256; k++) {
        float w0 = Wj[k * 128 + 0];
        float w1 = Wj[k * 128 + 32];
        float w2 = Wj[k * 128 + 64];
        float w3 = Wj[k * 128 + 96];
        #pragma unroll
        for (int r = 0; r < 8; r++) {
            float a = a_s[(rg * 8 + r) * 256 + k];
            acc[r][0] += a * w0;
            acc[r][1] += a * w1;
            acc[r][2] += a * w2;
            acc[r][3] += a * w3;
        }
    }

    #pragma unroll
    for (int r = 0; r < 8; r++) {
        int row = row0 + rg * 8 + r;
        if (row < nrows) {
            float* o = out + (size_t)row * 128 + jj;
            #pragma unroll
            for (int c = 0; c < 4; c++) o[c * 32] = acc[r][c];
        }
    }
}

// ---------------------------------------------------------------------------
// Kernel 5: out[i,j] = b2[j]  (spmm2 then atomically accumulates on top)
// ---------------------------------------------------------------------------
__global__ __launch_bounds__(256) void init_out_bias(
    const float* __restrict__ b, float* __restrict__ out) {
    int t = blockIdx.x * blockDim.x + threadIdx.x;  // float4 index
    if (t < N_NODES * (Y_DIM / 4)) {
        float4 bv = ((const float4*)b)[t & (Y_DIM / 4 - 1)];
        ((float4*)out)[t] = bv;
    }
}

extern "C" void kernel_launch(void* const* d_in, const int* in_sizes, int n_in,
                              void* d_out, int out_size, void* d_ws, size_t ws_size,
                              hipStream_t stream) {
    const float* x = (const float*)d_in[0];
    const float* adj_vals = (const float*)d_in[1];
    const int* adj_row = (const int*)d_in[2];
    const int* adj_col = (const int*)d_in[3];
    const float* W1 = (const float*)d_in[4];
    const float* b1 = (const float*)d_in[5];
    const float* W2 = (const float*)d_in[6];
    const float* b2 = (const float*)d_in[7];
    float* out = (float*)d_out;

    // Workspace layout (77 MB):
    //   inv  : N floats            @ 0
    //   agg1 : N*128 floats        @ 256 KB     (reused as hw after gemm1)
    //   h    : N*256 floats        @ 256KB + 25.6MB
    char* ws = (char*)d_ws;
    float* inv  = (float*)(ws);
    float* agg1 = (float*)(ws + 262144);
    float* h    = (float*)(ws + 262144 + (size_t)N_NODES * X_DIM * 4);
    float* hw   = agg1;  // agg1 dead after gemm1

    // 1. inv row sums of x
    hipLaunchKernelGGL(rowsum_inv_kernel, dim3((N_NODES * 64 + 255) / 256), dim3(256),
                       0, stream, x, inv);

    // 2. agg1 = 0 ; agg1 += A @ x_norm
    hipMemsetAsync(agg1, 0, (size_t)N_NODES * X_DIM * 4, stream);
    hipLaunchKernelGGL((spmm_scatter128<true>), dim3(N_EDGES * 32 / 256), dim3(256),
                       0, stream, x, adj_vals, adj_row, adj_col, inv, agg1);

    // 3. h = relu(agg1 @ W1 + b1)
    hipLaunchKernelGGL(gemm1_relu, dim3((N_NODES + 31) / 32), dim3(256),
                       0, stream, agg1, W1, b1, h, N_NODES);

    // 4. hw = h @ W2   (reordered: spmm(h) @ W2 == spmm(h @ W2))
    hipLaunchKernelGGL(gemm2_plain, dim3((N_NODES + 63) / 64), dim3(256),
                       0, stream, h, W2, hw, N_NODES);

    // 5. out = b2 ; out += A @ hw
    hipLaunchKernelGGL(init_out_bias, dim3((N_NODES * Y_DIM / 4 + 255) / 256), dim3(256),
                       0, stream, b2, out);
    hipLaunchKernelGGL((spmm_scatter128<false>), dim3(N_EDGES * 32 / 256), dim3(256),
                       0, stream, hw, adj_vals, adj_row, adj_col, (const float*)nullptr, out);
}

// Round 2
// 501.743 us; speedup vs baseline: 5.7970x; 5.7970x over previous
//
#include <hip/hip_runtime.h>

// Problem constants (fixed by the reference).
#define N_NODES 50000
#define N_EDGES 800000
#define X_DIM 128
#define H_DIM 256
#define Y_DIM 128

// ---------------------------------------------------------------------------
// Kernel 1: per-row reciprocal sum  inv[i] = 1 / (sum_d x[i,d] + 1e-4)
// ---------------------------------------------------------------------------
__global__ __launch_bounds__(256) void rowsum_inv_kernel(
    const float* __restrict__ x, float* __restrict__ inv) {
    int wave = (blockIdx.x * blockDim.x + threadIdx.x) >> 6;
    int lane = threadIdx.x & 63;
    if (wave >= N_NODES) return;
    const float2* xr = (const float2*)(x + (size_t)wave * X_DIM);
    float2 v = xr[lane];
    float s = v.x + v.y;
    #pragma unroll
    for (int off = 32; off > 0; off >>= 1) s += __shfl_down(s, off, 64);
    if (lane == 0) inv[wave] = 1.0f / (s + 1e-4f);
}

// ---------------------------------------------------------------------------
// CSR build step A: histogram edges per row.  counts must be pre-zeroed.
// ---------------------------------------------------------------------------
__global__ __launch_bounds__(256) void hist_kernel(
    const int* __restrict__ rows, int* __restrict__ counts) {
    int e = blockIdx.x * blockDim.x + threadIdx.x;
    if (e < N_EDGES) atomicAdd(&counts[rows[e]], 1);
}

// ---------------------------------------------------------------------------
// CSR build step B: exclusive scan of counts -> rowptr[N+1]. One block.
// ---------------------------------------------------------------------------
#define SCAN_T 1024
#define SCAN_CH 49  // 1024*49 = 50176 >= 50000
__global__ __launch_bounds__(SCAN_T) void scan_kernel(
    const int* __restrict__ counts, int* __restrict__ rowptr) {
    __shared__ int part[SCAN_T];
    int t = threadIdx.x;
    int begin = t * SCAN_CH;
    int end = begin + SCAN_CH; if (end > N_NODES) end = N_NODES;
    int s = 0;
    for (int i = begin; i < end; i++) s += counts[i];
    part[t] = s;
    __syncthreads();
    // Hillis-Steele inclusive scan
    for (int off = 1; off < SCAN_T; off <<= 1) {
        int v = (t >= off) ? part[t - off] : 0;
        __syncthreads();
        part[t] += v;
        __syncthreads();
    }
    int run = (t == 0) ? 0 : part[t - 1];
    for (int i = begin; i < end; i++) { rowptr[i] = run; run += counts[i]; }
    if (t == SCAN_T - 1) rowptr[N_NODES] = part[SCAN_T - 1];
}

// ---------------------------------------------------------------------------
// CSR build step C: scatter edges into row-sorted arrays. cursor pre-zeroed.
// ---------------------------------------------------------------------------
__global__ __launch_bounds__(256) void scatter_kernel(
    const int* __restrict__ rows, const int* __restrict__ cols,
    const float* __restrict__ vals, const int* __restrict__ rowptr,
    int* __restrict__ cursor, int* __restrict__ scol, float* __restrict__ sval) {
    int e = blockIdx.x * blockDim.x + threadIdx.x;
    if (e >= N_EDGES) return;
    int r = rows[e];
    int pos = rowptr[r] + atomicAdd(&cursor[r], 1);
    scol[pos] = cols[e];
    sval[pos] = vals[e];
}

// ---------------------------------------------------------------------------
// CSR spmm, D=128: one wave per row, lane owns 2 dims (float2).
// NORM: scale val by inv[col] (folds x row-normalization).
// BIAS: add bias[j] in epilogue (folds b2 for the final layer).
// Output written exactly once per row -> no atomics, zero rows included.
// ---------------------------------------------------------------------------
template <bool NORM, bool BIAS>
__global__ __launch_bounds__(256) void spmm_csr128(
    const float* __restrict__ feat, const int* __restrict__ rowptr,
    const int* __restrict__ scol, const float* __restrict__ sval,
    const float* __restrict__ inv, const float* __restrict__ bias,
    float* __restrict__ out) {
    int row = (blockIdx.x * blockDim.x + threadIdx.x) >> 6;
    int lane = threadIdx.x & 63;
    if (row >= N_NODES) return;
    int start = rowptr[row];
    int end = rowptr[row + 1];
    const float2* feat2 = (const float2*)feat;
    float2 acc = make_float2(0.f, 0.f);
    for (int base = start; base < end; base += 64) {
        int n = end - base;
        if (n > 64) n = 64;
        int c = 0;
        float v = 0.f;
        if (lane < n) {
            c = scol[base + lane];
            v = sval[base + lane];
            if (NORM) v *= inv[c];
        }
        for (int j = 0; j < n; j++) {
            int cj = __shfl(c, j, 64);
            float vj = __shfl(v, j, 64);
            float2 f = feat2[(size_t)cj * 64 + lane];
            acc.x += vj * f.x;
            acc.y += vj * f.y;
        }
    }
    if (BIAS) {
        float2 b = ((const float2*)bias)[lane];
        acc.x += b.x;
        acc.y += b.y;
    }
    ((float2*)out)[(size_t)row * 64 + lane] = acc;
}

// ---------------------------------------------------------------------------
// GEMM 1: h = relu(A @ W1 + b1), A:[n,128], W1:[128,256]
// ---------------------------------------------------------------------------
__global__ __launch_bounds__(256) void gemm1_relu(
    const float* __restrict__ A, const float* __restrict__ W,
    const float* __restrict__ bias, float* __restrict__ out, int nrows) {
    __shared__ float a_s[32 * 128];  // 16 KB
    const int tx = threadIdx.x;
    const int jj = tx & 63;
    const int rg = tx >> 6;  // rows rg*8 .. rg*8+7
    const int row0 = blockIdx.x * 32;

    {
        const float4* src = (const float4*)A;
        float4* dst = (float4*)a_s;
        #pragma unroll
        for (int i = 0; i < 4; i++) {
            int idx = tx + i * 256;
            int rr = idx >> 5;
            float4 v = make_float4(0.f, 0.f, 0.f, 0.f);
            if (row0 + rr < nrows) v = src[(size_t)row0 * 32 + idx];
            dst[idx] = v;
        }
    }
    __syncthreads();

    float acc[8][4];
    #pragma unroll
    for (int r = 0; r < 8; r++)
        #pragma unroll
        for (int c = 0; c < 4; c++) acc[r][c] = 0.f;

    const float* Wj = W + jj;
    #pragma unroll 4
    for (int k = 0; k < 128; k++) {
        float w0 = Wj[k * 256 + 0];
        float w1 = Wj[k * 256 + 64];
        float w2 = Wj[k * 256 + 128];
        float w3 = Wj[k * 256 + 192];
        #pragma unroll
        for (int r = 0; r < 8; r++) {
            float a = a_s[(rg * 8 + r) * 128 + k];
            acc[r][0] += a * w0;
            acc[r][1] += a * w1;
            acc[r][2] += a * w2;
            acc[r][3] += a * w3;
        }
    }

    float b[4];
    #pragma unroll
    for (int c = 0; c < 4; c++) b[c] = bias[jj + c * 64];
    #pragma unroll
    for (int r = 0; r < 8; r++) {
        int row = row0 + rg * 8 + r;
        if (row < nrows) {
            float* o = out + (size_t)row * 256 + jj;
            #pragma unroll
            for (int c = 0; c < 4; c++) {
                float v = acc[r][c] + b[c];
                o[c * 64] = v > 0.f ? v : 0.f;
            }
        }
    }
}

// ---------------------------------------------------------------------------
// GEMM 2: hw = h @ W2, h:[n,256], W2:[256,128]
// ---------------------------------------------------------------------------
__global__ __launch_bounds__(256) void gemm2_plain(
    const float* __restrict__ A, const float* __restrict__ W,
    float* __restrict__ out, int nrows) {
    __shared__ float a_s[64 * 256];  // 64 KB
    const int tx = threadIdx.x;
    const int jj = tx & 31;
    const int rg = tx >> 5;
    const int row0 = blockIdx.x * 64;

    {
        const float4* src = (const float4*)A;
        float4* dst = (float4*)a_s;
        #pragma unroll
        for (int i = 0; i < 16; i++) {
            int idx = tx + i * 256;
            int rr = idx >> 6;
            float4 v = make_float4(0.f, 0.f, 0.f, 0.f);
            if (row0 + rr < nrows) v = src[(size_t)row0 * 64 + idx];
            dst[idx] = v;
        }
    }
    __syncthreads();

    float acc[8][4];
    #pragma unroll
    for (int r = 0; r < 8; r++)
        #pragma unroll
        for (int c = 0; c < 4; c++) acc[r][c] = 0.f;

    const float* Wj = W + jj;
    #pragma unroll 4
    for (int k = 0; k < 256; k++) {
        float w0 = Wj[k * 128 + 0];
        float w1 = Wj[k * 128 + 32];
        float w2 = Wj[k * 128 + 64];
        float w3 = Wj[k * 128 + 96];
        #pragma unroll
        for (int r = 0; r < 8; r++) {
            float a = a_s[(rg * 8 + r) * 256 + k];
            acc[r][0] += a * w0;
            acc[r][1] += a * w1;
            acc[r][2] += a * w2;
            acc[r][3] += a * w3;
        }
    }

    #pragma unroll
    for (int r = 0; r < 8; r++) {
        int row = row0 + rg * 8 + r;
        if (row < nrows) {
            float* o = out + (size_t)row * 128 + jj;
            #pragma unroll
            for (int c = 0; c < 4; c++) o[c * 32] = acc[r][c];
        }
    }
}

extern "C" void kernel_launch(void* const* d_in, const int* in_sizes, int n_in,
                              void* d_out, int out_size, void* d_ws, size_t ws_size,
                              hipStream_t stream) {
    const float* x = (const float*)d_in[0];
    const float* adj_vals = (const float*)d_in[1];
    const int* adj_row = (const int*)d_in[2];
    const int* adj_col = (const int*)d_in[3];
    const float* W1 = (const float*)d_in[4];
    const float* b1 = (const float*)d_in[5];
    const float* W2 = (const float*)d_in[6];
    const float* b2 = (const float*)d_in[7];
    float* out = (float*)d_out;

    // Workspace layout (~85.2 MB):
    char* ws = (char*)d_ws;
    float* inv    = (float*)(ws + 0);               // 200 KB
    int*   rowptr = (int*)  (ws + (256 << 10));     // 200 KB
    int*   cursor = (int*)  (ws + (512 << 10));     // 200 KB (counts, then cursors)
    int*   scol   = (int*)  (ws + (768 << 10));     // 3.2 MB
    float* sval   = (float*)(ws + (4 << 20));       // 3.2 MB
    float* agg1   = (float*)(ws + (8 << 20));       // 25.6 MB (reused as hw)
    float* h      = (float*)(ws + (34 << 20));      // 51.2 MB
    float* hw     = agg1;                           // agg1 dead after gemm1

    // 1. inv row sums of x
    hipLaunchKernelGGL(rowsum_inv_kernel, dim3((N_NODES * 64 + 255) / 256), dim3(256),
                       0, stream, x, inv);

    // 2. CSR build: histogram -> scan -> scatter
    hipMemsetAsync(cursor, 0, (N_NODES + 1) * sizeof(int), stream);
    hipLaunchKernelGGL(hist_kernel, dim3((N_EDGES + 255) / 256), dim3(256),
                       0, stream, adj_row, cursor);
    hipLaunchKernelGGL(scan_kernel, dim3(1), dim3(SCAN_T),
                       0, stream, cursor, rowptr);
    hipMemsetAsync(cursor, 0, (N_NODES + 1) * sizeof(int), stream);
    hipLaunchKernelGGL(scatter_kernel, dim3((N_EDGES + 255) / 256), dim3(256),
                       0, stream, adj_row, adj_col, adj_vals, rowptr, cursor, scol, sval);

    // 3. agg1 = A @ x_norm   (norm folded via inv[col])
    hipLaunchKernelGGL((spmm_csr128<true, false>), dim3((N_NODES * 64 + 255) / 256), dim3(256),
                       0, stream, x, rowptr, scol, sval, inv, (const float*)nullptr, agg1);

    // 4. h = relu(agg1 @ W1 + b1)
    hipLaunchKernelGGL(gemm1_relu, dim3((N_NODES + 31) / 32), dim3(256),
                       0, stream, agg1, W1, b1, h, N_NODES);

    // 5. hw = h @ W2   (reordered: spmm(h) @ W2 == spmm(h @ W2))
    hipLaunchKernelGGL(gemm2_plain, dim3((N_NODES + 63) / 64), dim3(256),
                       0, stream, h, W2, hw, N_NODES);

    // 6. out = A @ hw + b2
    hipLaunchKernelGGL((spmm_csr128<false, true>), dim3((N_NODES * 64 + 255) / 256), dim3(256),
                       0, stream, hw, rowptr, scol, sval, (const float*)nullptr, b2, out);
}

// Round 3
// 418.682 us; speedup vs baseline: 6.9470x; 1.1984x over previous
//
#include <hip/hip_runtime.h>

// Problem constants (fixed by the reference).
#define N_NODES 50000
#define N_EDGES 800000
#define X_DIM 128
#define H_DIM 256
#define Y_DIM 128

typedef unsigned int uint32;
typedef unsigned short ushort16;
typedef __attribute__((ext_vector_type(8))) short short8;
typedef __attribute__((ext_vector_type(4))) float floatx4;

// bf16 helpers (round-to-nearest-even; no NaN expected in this workload)
__device__ inline ushort16 f2bf(float f) {
    uint32 u = __float_as_uint(f);
    return (ushort16)((u + 0x7FFFu + ((u >> 16) & 1u)) >> 16);
}
__device__ inline float bf_lo(uint32 u) { return __uint_as_float(u << 16); }
__device__ inline float bf_hi(uint32 u) { return __uint_as_float(u & 0xFFFF0000u); }

// ---------------------------------------------------------------------------
// Kernel 1: fused row-normalize + bf16 convert:  xb[i,:] = bf16(x[i,:]/(sum+1e-4))
// One wave per row; lane owns 2 dims (float2 in, bf16x2 out).
// ---------------------------------------------------------------------------
__global__ __launch_bounds__(256) void norm_bf16_kernel(
    const float* __restrict__ x, uint32* __restrict__ xb) {
    int row = (blockIdx.x * blockDim.x + threadIdx.x) >> 6;
    int lane = threadIdx.x & 63;
    if (row >= N_NODES) return;
    float2 v = ((const float2*)x)[(size_t)row * 64 + lane];
    float s = v.x + v.y;
    #pragma unroll
    for (int off = 32; off > 0; off >>= 1) s += __shfl_xor(s, off, 64);
    float inv = 1.0f / (s + 1e-4f);
    uint32 lo = (uint32)f2bf(v.x * inv);
    uint32 hi = (uint32)f2bf(v.y * inv);
    xb[(size_t)row * 64 + lane] = lo | (hi << 16);
}

// ---------------------------------------------------------------------------
// Kernel 2: convert W1, W2 to bf16 (32768 elements each)
// ---------------------------------------------------------------------------
__global__ __launch_bounds__(256) void convert_w_kernel(
    const float* __restrict__ W1, const float* __restrict__ W2,
    ushort16* __restrict__ W1b, ushort16* __restrict__ W2b) {
    int t = blockIdx.x * blockDim.x + threadIdx.x;
    if (t < X_DIM * H_DIM) W1b[t] = f2bf(W1[t]);
    if (t < H_DIM * Y_DIM) W2b[t] = f2bf(W2[t]);
}

// ---------------------------------------------------------------------------
// CSR build: histogram -> scan -> scatter (edges as int2 {col, val-bits})
// ---------------------------------------------------------------------------
__global__ __launch_bounds__(256) void hist_kernel(
    const int* __restrict__ rows, int* __restrict__ counts) {
    int e = blockIdx.x * blockDim.x + threadIdx.x;
    if (e < N_EDGES) atomicAdd(&counts[rows[e]], 1);
}

#define SCAN_T 1024
#define SCAN_CH 49  // 1024*49 = 50176 >= 50000
__global__ __launch_bounds__(SCAN_T) void scan_kernel(
    const int* __restrict__ counts, int* __restrict__ rowptr) {
    __shared__ int part[SCAN_T];
    int t = threadIdx.x;
    int begin = t * SCAN_CH;
    int end = begin + SCAN_CH; if (end > N_NODES) end = N_NODES;
    int s = 0;
    for (int i = begin; i < end; i++) s += counts[i];
    part[t] = s;
    __syncthreads();
    for (int off = 1; off < SCAN_T; off <<= 1) {
        int v = (t >= off) ? part[t - off] : 0;
        __syncthreads();
        part[t] += v;
        __syncthreads();
    }
    int run = (t == 0) ? 0 : part[t - 1];
    for (int i = begin; i < end; i++) { rowptr[i] = run; run += counts[i]; }
    if (t == SCAN_T - 1) rowptr[N_NODES] = part[SCAN_T - 1];
}

__global__ __launch_bounds__(256) void scatter_kernel(
    const int* __restrict__ rows, const int* __restrict__ cols,
    const float* __restrict__ vals, const int* __restrict__ rowptr,
    int* __restrict__ cursor, int2* __restrict__ edges) {
    int e = blockIdx.x * blockDim.x + threadIdx.x;
    if (e >= N_EDGES) return;
    int r = rows[e];
    int pos = rowptr[r] + atomicAdd(&cursor[r], 1);
    edges[pos] = make_int2(cols[e], __float_as_int(vals[e]));
}

// ---------------------------------------------------------------------------
// CSR spmm (bf16 feat -> bf16 out), D=128. One wave/row, lane owns 2 dims.
// Edge loop unrolled x4 with independent accumulators for memory-level ||ism.
// ---------------------------------------------------------------------------
__global__ __launch_bounds__(256) void spmm_csr_bf16(
    const uint32* __restrict__ feat, const int* __restrict__ rowptr,
    const int2* __restrict__ edges, uint32* __restrict__ out) {
    int row = (blockIdx.x * blockDim.x + threadIdx.x) >> 6;
    int lane = threadIdx.x & 63;
    if (row >= N_NODES) return;
    int start = rowptr[row], end = rowptr[row + 1];
    float ax0 = 0.f, ay0 = 0.f, ax1 = 0.f, ay1 = 0.f;
    float ax2 = 0.f, ay2 = 0.f, ax3 = 0.f, ay3 = 0.f;
    for (int base = start; base < end; base += 64) {
        int n = end - base; if (n > 64) n = 64;
        int2 ev = make_int2(0, 0);
        if (lane < n) ev = edges[base + lane];
        int c = ev.x; float v = __int_as_float(ev.y);
        int j = 0;
        for (; j + 4 <= n; j += 4) {
            int c0 = __shfl(c, j, 64), c1 = __shfl(c, j + 1, 64);
            int c2 = __shfl(c, j + 2, 64), c3 = __shfl(c, j + 3, 64);
            float v0 = __shfl(v, j, 64), v1 = __shfl(v, j + 1, 64);
            float v2 = __shfl(v, j + 2, 64), v3 = __shfl(v, j + 3, 64);
            uint32 f0 = feat[(size_t)c0 * 64 + lane];
            uint32 f1 = feat[(size_t)c1 * 64 + lane];
            uint32 f2 = feat[(size_t)c2 * 64 + lane];
            uint32 f3 = feat[(size_t)c3 * 64 + lane];
            ax0 += v0 * bf_lo(f0); ay0 += v0 * bf_hi(f0);
            ax1 += v1 * bf_lo(f1); ay1 += v1 * bf_hi(f1);
            ax2 += v2 * bf_lo(f2); ay2 += v2 * bf_hi(f2);
            ax3 += v3 * bf_lo(f3); ay3 += v3 * bf_hi(f3);
        }
        for (; j < n; j++) {
            int c0 = __shfl(c, j, 64);
            float v0 = __shfl(v, j, 64);
            uint32 f0 = feat[(size_t)c0 * 64 + lane];
            ax0 += v0 * bf_lo(f0); ay0 += v0 * bf_hi(f0);
        }
    }
    float ax = (ax0 + ax1) + (ax2 + ax3);
    float ay = (ay0 + ay1) + (ay2 + ay3);
    out[(size_t)row * 64 + lane] = (uint32)f2bf(ax) | ((uint32)f2bf(ay) << 16);
}

// ---------------------------------------------------------------------------
// CSR spmm (fp32 feat -> fp32 out + bias), D=128. Same structure.
// ---------------------------------------------------------------------------
__global__ __launch_bounds__(256) void spmm_csr_f32(
    const float* __restrict__ feat, const int* __restrict__ rowptr,
    const int2* __restrict__ edges, const float* __restrict__ bias,
    float* __restrict__ out) {
    int row = (blockIdx.x * blockDim.x + threadIdx.x) >> 6;
    int lane = threadIdx.x & 63;
    if (row >= N_NODES) return;
    int start = rowptr[row], end = rowptr[row + 1];
    const float2* feat2 = (const float2*)feat;
    float ax0 = 0.f, ay0 = 0.f, ax1 = 0.f, ay1 = 0.f;
    float ax2 = 0.f, ay2 = 0.f, ax3 = 0.f, ay3 = 0.f;
    for (int base = start; base < end; base += 64) {
        int n = end - base; if (n > 64) n = 64;
        int2 ev = make_int2(0, 0);
        if (lane < n) ev = edges[base + lane];
        int c = ev.x; float v = __int_as_float(ev.y);
        int j = 0;
        for (; j + 4 <= n; j += 4) {
            int c0 = __shfl(c, j, 64), c1 = __shfl(c, j + 1, 64);
            int c2 = __shfl(c, j + 2, 64), c3 = __shfl(c, j + 3, 64);
            float v0 = __shfl(v, j, 64), v1 = __shfl(v, j + 1, 64);
            float v2 = __shfl(v, j + 2, 64), v3 = __shfl(v, j + 3, 64);
            float2 f0 = feat2[(size_t)c0 * 64 + lane];
            float2 f1 = feat2[(size_t)c1 * 64 + lane];
            float2 f2 = feat2[(size_t)c2 * 64 + lane];
            float2 f3 = feat2[(size_t)c3 * 64 + lane];
            ax0 += v0 * f0.x; ay0 += v0 * f0.y;
            ax1 += v1 * f1.x; ay1 += v1 * f1.y;
            ax2 += v2 * f2.x; ay2 += v2 * f2.y;
            ax3 += v3 * f3.x; ay3 += v3 * f3.y;
        }
        for (; j < n; j++) {
            int c0 = __shfl(c, j, 64);
            float v0 = __shfl(v, j, 64);
            float2 f0 = feat2[(size_t)c0 * 64 + lane];
            ax0 += v0 * f0.x; ay0 += v0 * f0.y;
        }
    }
    float2 b = ((const float2*)bias)[lane];
    float ax = (ax0 + ax1) + (ax2 + ax3) + b.x;
    float ay = (ay0 + ay1) + (ay2 + ay3) + b.y;
    ((float2*)out)[(size_t)row * 64 + lane] = make_float2(ax, ay);
}

// ---------------------------------------------------------------------------
// bf16 MFMA GEMM: out[n, NOUT] = act(A[n, K] @ B[K, NOUT] + bias)
// Block = 256 thr (4 waves). Tile M=64, N=64, K chunked by 64.
// LDS stride 72 ushorts (144 B) -> b128 fragment reads are 2-way (free).
// Fragment layouts (verified m89/m120): A/B lane&15 = m/n, k = quad*8+j;
// C/D col = lane&15, row = quad*4 + reg.
// ---------------------------------------------------------------------------
template <int K, int NOUT, bool RELU, bool OUT_BF16>
__global__ __launch_bounds__(256) void gemm_mfma(
    const ushort16* __restrict__ A, const ushort16* __restrict__ Bw,
    const float* __restrict__ bias, void* __restrict__ outv, int nrows) {
    __shared__ ushort16 a_s[64 * 72];
    __shared__ ushort16 b_s[64 * 72];
    const int tx = threadIdx.x;
    const int wave = tx >> 6, lane = tx & 63;
    const int quad = lane >> 4, l16 = lane & 15;
    const int row0 = blockIdx.x * 64, col0 = blockIdx.y * 64;

    floatx4 acc[4];
    #pragma unroll
    for (int i = 0; i < 4; i++)
        #pragma unroll
        for (int j = 0; j < 4; j++) acc[i][j] = 0.f;

    #pragma unroll
    for (int kc = 0; kc < K / 64; kc++) {
        // stage A chunk (64 rows x 64 k) as uints, conflict-free
        const uint32* Ag = (const uint32*)A;
        #pragma unroll
        for (int i = 0; i < 8; i++) {
            int idx = tx + i * 256;
            int r = idx >> 5, c = idx & 31;
            uint32 v = 0;
            if (row0 + r < nrows) v = Ag[(size_t)(row0 + r) * (K / 2) + kc * 32 + c];
            *(uint32*)&a_s[r * 72 + c * 2] = v;
        }
        // stage B chunk transposed: b_s[n][k']
        #pragma unroll
        for (int i = 0; i < 16; i++) {
            int idx = tx + i * 256;
            int kr = idx >> 6, nc = idx & 63;
            b_s[nc * 72 + kr] = Bw[(size_t)(kc * 64 + kr) * NOUT + col0 + nc];
        }
        __syncthreads();
        #pragma unroll
        for (int kk = 0; kk < 2; kk++) {
            short8 af = *(const short8*)&a_s[(wave * 16 + l16) * 72 + kk * 32 + quad * 8];
            #pragma unroll
            for (int ct = 0; ct < 4; ct++) {
                short8 bf = *(const short8*)&b_s[(ct * 16 + l16) * 72 + kk * 32 + quad * 8];
                acc[ct] = __builtin_amdgcn_mfma_f32_16x16x32_bf16(af, bf, acc[ct], 0, 0, 0);
            }
        }
        __syncthreads();
    }

    #pragma unroll
    for (int ct = 0; ct < 4; ct++) {
        int col = col0 + ct * 16 + l16;
        float bv = bias ? bias[col] : 0.f;
        #pragma unroll
        for (int reg = 0; reg < 4; reg++) {
            int row = row0 + wave * 16 + quad * 4 + reg;
            if (row < nrows) {
                float val = acc[ct][reg] + bv;
                if (RELU) val = val > 0.f ? val : 0.f;
                if (OUT_BF16)
                    ((ushort16*)outv)[(size_t)row * NOUT + col] = f2bf(val);
                else
                    ((float*)outv)[(size_t)row * NOUT + col] = val;
            }
        }
    }
}

extern "C" void kernel_launch(void* const* d_in, const int* in_sizes, int n_in,
                              void* d_out, int out_size, void* d_ws, size_t ws_size,
                              hipStream_t stream) {
    const float* x = (const float*)d_in[0];
    const float* adj_vals = (const float*)d_in[1];
    const int* adj_row = (const int*)d_in[2];
    const int* adj_col = (const int*)d_in[3];
    const float* W1 = (const float*)d_in[4];
    const float* b1 = (const float*)d_in[5];
    const float* W2 = (const float*)d_in[6];
    const float* b2 = (const float*)d_in[7];
    float* out = (float*)d_out;

    // Workspace layout (~83.8 MB):
    char* ws = (char*)d_ws;
    uint32*   xb     = (uint32*)  (ws + 0);            // 12.8 MB (bf16 x-norm)
    uint32*   agg1   = (uint32*)  (ws + 12800000);     // 12.8 MB (bf16)
    ushort16* h      = (ushort16*)(ws + 25600000);     // 25.6 MB (bf16)
    float*    hw     = (float*)   (ws + 51200000);     // 25.6 MB (fp32)
    int2*     edges  = (int2*)    (ws + 76800000);     //  6.4 MB
    int*      rowptr = (int*)     (ws + 83200000);     //  200 KB
    int*      cursor = (int*)     (ws + 83400008);     //  200 KB
    ushort16* W1b    = (ushort16*)(ws + 83600016);     //   64 KB
    ushort16* W2b    = (ushort16*)(ws + 83665552);     //   64 KB

    // 1. x-hat = bf16(row-normalized x)
    hipLaunchKernelGGL(norm_bf16_kernel, dim3((N_NODES * 64 + 255) / 256), dim3(256),
                       0, stream, x, xb);
    // 2. weights -> bf16
    hipLaunchKernelGGL(convert_w_kernel, dim3((H_DIM * 256 + 255) / 256 / 2 * 2), dim3(256),
                       0, stream, W1, W2, W1b, W2b);

    // 3. CSR build
    hipMemsetAsync(cursor, 0, (N_NODES + 1) * sizeof(int), stream);
    hipLaunchKernelGGL(hist_kernel, dim3((N_EDGES + 255) / 256), dim3(256),
                       0, stream, adj_row, cursor);
    hipLaunchKernelGGL(scan_kernel, dim3(1), dim3(SCAN_T),
                       0, stream, cursor, rowptr);
    hipMemsetAsync(cursor, 0, (N_NODES + 1) * sizeof(int), stream);
    hipLaunchKernelGGL(scatter_kernel, dim3((N_EDGES + 255) / 256), dim3(256),
                       0, stream, adj_row, adj_col, adj_vals, rowptr, cursor, edges);

    // 4. agg1 = A @ x-hat   (bf16 gather, bf16 out)
    hipLaunchKernelGGL(spmm_csr_bf16, dim3((N_NODES * 64 + 255) / 256), dim3(256),
                       0, stream, xb, rowptr, edges, agg1);

    // 5. h = relu(agg1 @ W1 + b1)   [MFMA bf16]
    hipLaunchKernelGGL((gemm_mfma<128, 256, true, true>), dim3((N_NODES + 63) / 64, 4), dim3(256),
                       0, stream, (const ushort16*)agg1, W1b, b1, (void*)h, N_NODES);

    // 6. hw = h @ W2   [MFMA bf16, fp32 out]
    hipLaunchKernelGGL((gemm_mfma<256, 128, false, false>), dim3((N_NODES + 63) / 64, 2), dim3(256),
                       0, stream, h, W2b, (const float*)nullptr, (void*)hw, N_NODES);

    // 7. out = A @ hw + b2   (fp32 gather)
    hipLaunchKernelGGL(spmm_csr_f32, dim3((N_NODES * 64 + 255) / 256), dim3(256),
                       0, stream, hw, rowptr, edges, b2, out);
}

// Round 4
// 354.933 us; speedup vs baseline: 8.1947x; 1.1796x over previous
//
#include <hip/hip_runtime.h>

// Problem constants (fixed by the reference).
#define N_NODES 50000
#define N_EDGES 800000
#define X_DIM 128
#define H_DIM 256
#define Y_DIM 128

typedef unsigned int uint32;
typedef unsigned short ushort16;
typedef __attribute__((ext_vector_type(8))) short short8;
typedef __attribute__((ext_vector_type(4))) float floatx4;

// bf16 helpers (round-to-nearest-even; no NaN expected in this workload)
__device__ inline ushort16 f2bf(float f) {
    uint32 u = __float_as_uint(f);
    return (ushort16)((u + 0x7FFFu + ((u >> 16) & 1u)) >> 16);
}
__device__ inline float bf_lo(uint32 u) { return __uint_as_float(u << 16); }
__device__ inline float bf_hi(uint32 u) { return __uint_as_float(u & 0xFFFF0000u); }

// ---------------------------------------------------------------------------
// Kernel 1: fused row-normalize + bf16 convert:  xb[i,:] = bf16(x[i,:]/(sum+1e-4))
// ---------------------------------------------------------------------------
__global__ __launch_bounds__(256) void norm_bf16_kernel(
    const float* __restrict__ x, uint32* __restrict__ xb) {
    int row = (blockIdx.x * blockDim.x + threadIdx.x) >> 6;
    int lane = threadIdx.x & 63;
    if (row >= N_NODES) return;
    float2 v = ((const float2*)x)[(size_t)row * 64 + lane];
    float s = v.x + v.y;
    #pragma unroll
    for (int off = 32; off > 0; off >>= 1) s += __shfl_xor(s, off, 64);
    float inv = 1.0f / (s + 1e-4f);
    uint32 lo = (uint32)f2bf(v.x * inv);
    uint32 hi = (uint32)f2bf(v.y * inv);
    xb[(size_t)row * 64 + lane] = lo | (hi << 16);
}

// ---------------------------------------------------------------------------
// Kernel 2: convert W1, W2 to bf16 (32768 elements each)
// ---------------------------------------------------------------------------
__global__ __launch_bounds__(256) void convert_w_kernel(
    const float* __restrict__ W1, const float* __restrict__ W2,
    ushort16* __restrict__ W1b, ushort16* __restrict__ W2b) {
    int t = blockIdx.x * blockDim.x + threadIdx.x;
    if (t < X_DIM * H_DIM) W1b[t] = f2bf(W1[t]);
    if (t < H_DIM * Y_DIM) W2b[t] = f2bf(W2[t]);
}

// ---------------------------------------------------------------------------
// CSR build: histogram -> hierarchical scan (3 kernels) -> scatter
// ---------------------------------------------------------------------------
__global__ __launch_bounds__(256) void hist_kernel(
    const int* __restrict__ rows, int* __restrict__ counts) {
    int e = blockIdx.x * blockDim.x + threadIdx.x;
    if (e < N_EDGES) atomicAdd(&counts[rows[e]], 1);
}

#define SCAN_BLOCKS 196  // ceil(50000/256)

// (a) per-block partial sums over 256-element chunks
__global__ __launch_bounds__(256) void scan_partial_kernel(
    const int* __restrict__ counts, int* __restrict__ partials) {
    __shared__ int wsum[4];
    int t = threadIdx.x;
    int i = blockIdx.x * 256 + t;
    int s = (i < N_NODES) ? counts[i] : 0;
    #pragma unroll
    for (int off = 32; off > 0; off >>= 1) s += __shfl_down(s, off, 64);
    if ((t & 63) == 0) wsum[t >> 6] = s;
    __syncthreads();
    if (t == 0) partials[blockIdx.x] = wsum[0] + wsum[1] + wsum[2] + wsum[3];
}

// (b) exclusive scan of the 196 partials (single tiny block), in place
__global__ __launch_bounds__(256) void scan_top_kernel(
    int* __restrict__ partials, int* __restrict__ rowptr) {
    __shared__ int part[256];
    int t = threadIdx.x;
    int v = (t < SCAN_BLOCKS) ? partials[t] : 0;
    part[t] = v;
    __syncthreads();
    #pragma unroll
    for (int off = 1; off < 256; off <<= 1) {
        int u = (t >= off) ? part[t - off] : 0;
        __syncthreads();
        part[t] += u;
        __syncthreads();
    }
    if (t < SCAN_BLOCKS) partials[t] = part[t] - v;  // exclusive
    if (t == 0) rowptr[N_NODES] = N_EDGES;           // total is static
}

// (c) per-block exclusive scan of its chunk + block offset -> rowptr
__global__ __launch_bounds__(256) void scan_apply_kernel(
    const int* __restrict__ counts, const int* __restrict__ partials,
    int* __restrict__ rowptr) {
    __shared__ int part[256];
    int t = threadIdx.x;
    int i = blockIdx.x * 256 + t;
    int v = (i < N_NODES) ? counts[i] : 0;
    part[t] = v;
    __syncthreads();
    #pragma unroll
    for (int off = 1; off < 256; off <<= 1) {
        int u = (t >= off) ? part[t - off] : 0;
        __syncthreads();
        part[t] += u;
        __syncthreads();
    }
    if (i < N_NODES) rowptr[i] = partials[blockIdx.x] + part[t] - v;
}

__global__ __launch_bounds__(256) void scatter_kernel(
    const int* __restrict__ rows, const int* __restrict__ cols,
    const float* __restrict__ vals, const int* __restrict__ rowptr,
    int* __restrict__ cursor, int2* __restrict__ edges) {
    int e = blockIdx.x * blockDim.x + threadIdx.x;
    if (e >= N_EDGES) return;
    int r = rows[e];
    int pos = rowptr[r] + atomicAdd(&cursor[r], 1);
    edges[pos] = make_int2(cols[e], __float_as_int(vals[e]));
}

// ---------------------------------------------------------------------------
// CSR spmm (bf16 feat -> bf16 out), D=128. One wave/row, lane owns 2 dims.
// Edge loop 8-wide: 8 independent gathers in flight (gather-latency bound).
// ---------------------------------------------------------------------------
__global__ __launch_bounds__(256) void spmm_csr_bf16(
    const uint32* __restrict__ feat, const int* __restrict__ rowptr,
    const int2* __restrict__ edges, uint32* __restrict__ out) {
    int row = (blockIdx.x * blockDim.x + threadIdx.x) >> 6;
    int lane = threadIdx.x & 63;
    if (row >= N_NODES) return;
    int start = rowptr[row], end = rowptr[row + 1];
    float ax0 = 0.f, ay0 = 0.f, ax1 = 0.f, ay1 = 0.f;
    float ax2 = 0.f, ay2 = 0.f, ax3 = 0.f, ay3 = 0.f;
    for (int base = start; base < end; base += 64) {
        int n = end - base; if (n > 64) n = 64;
        int2 ev = make_int2(0, 0);
        if (lane < n) ev = edges[base + lane];
        int c = ev.x; float v = __int_as_float(ev.y);
        int j = 0;
        for (; j + 8 <= n; j += 8) {
            int c0 = __shfl(c, j, 64), c1 = __shfl(c, j + 1, 64);
            int c2 = __shfl(c, j + 2, 64), c3 = __shfl(c, j + 3, 64);
            int c4 = __shfl(c, j + 4, 64), c5 = __shfl(c, j + 5, 64);
            int c6 = __shfl(c, j + 6, 64), c7 = __shfl(c, j + 7, 64);
            float v0 = __shfl(v, j, 64), v1 = __shfl(v, j + 1, 64);
            float v2 = __shfl(v, j + 2, 64), v3 = __shfl(v, j + 3, 64);
            float v4 = __shfl(v, j + 4, 64), v5 = __shfl(v, j + 5, 64);
            float v6 = __shfl(v, j + 6, 64), v7 = __shfl(v, j + 7, 64);
            uint32 f0 = feat[(size_t)c0 * 64 + lane];
            uint32 f1 = feat[(size_t)c1 * 64 + lane];
            uint32 f2 = feat[(size_t)c2 * 64 + lane];
            uint32 f3 = feat[(size_t)c3 * 64 + lane];
            uint32 f4 = feat[(size_t)c4 * 64 + lane];
            uint32 f5 = feat[(size_t)c5 * 64 + lane];
            uint32 f6 = feat[(size_t)c6 * 64 + lane];
            uint32 f7 = feat[(size_t)c7 * 64 + lane];
            ax0 += v0 * bf_lo(f0); ay0 += v0 * bf_hi(f0);
            ax1 += v1 * bf_lo(f1); ay1 += v1 * bf_hi(f1);
            ax2 += v2 * bf_lo(f2); ay2 += v2 * bf_hi(f2);
            ax3 += v3 * bf_lo(f3); ay3 += v3 * bf_hi(f3);
            ax0 += v4 * bf_lo(f4); ay0 += v4 * bf_hi(f4);
            ax1 += v5 * bf_lo(f5); ay1 += v5 * bf_hi(f5);
            ax2 += v6 * bf_lo(f6); ay2 += v6 * bf_hi(f6);
            ax3 += v7 * bf_lo(f7); ay3 += v7 * bf_hi(f7);
        }
        for (; j + 4 <= n; j += 4) {
            int c0 = __shfl(c, j, 64), c1 = __shfl(c, j + 1, 64);
            int c2 = __shfl(c, j + 2, 64), c3 = __shfl(c, j + 3, 64);
            float v0 = __shfl(v, j, 64), v1 = __shfl(v, j + 1, 64);
            float v2 = __shfl(v, j + 2, 64), v3 = __shfl(v, j + 3, 64);
            uint32 f0 = feat[(size_t)c0 * 64 + lane];
            uint32 f1 = feat[(size_t)c1 * 64 + lane];
            uint32 f2 = feat[(size_t)c2 * 64 + lane];
            uint32 f3 = feat[(size_t)c3 * 64 + lane];
            ax0 += v0 * bf_lo(f0); ay0 += v0 * bf_hi(f0);
            ax1 += v1 * bf_lo(f1); ay1 += v1 * bf_hi(f1);
            ax2 += v2 * bf_lo(f2); ay2 += v2 * bf_hi(f2);
            ax3 += v3 * bf_lo(f3); ay3 += v3 * bf_hi(f3);
        }
        for (; j < n; j++) {
            int c0 = __shfl(c, j, 64);
            float v0 = __shfl(v, j, 64);
            uint32 f0 = feat[(size_t)c0 * 64 + lane];
            ax0 += v0 * bf_lo(f0); ay0 += v0 * bf_hi(f0);
        }
    }
    float ax = (ax0 + ax1) + (ax2 + ax3);
    float ay = (ay0 + ay1) + (ay2 + ay3);
    out[(size_t)row * 64 + lane] = (uint32)f2bf(ax) | ((uint32)f2bf(ay) << 16);
}

// ---------------------------------------------------------------------------
// CSR spmm (fp32 feat -> fp32 out + bias), D=128. Same 8-wide structure.
// ---------------------------------------------------------------------------
__global__ __launch_bounds__(256) void spmm_csr_f32(
    const float* __restrict__ feat, const int* __restrict__ rowptr,
    const int2* __restrict__ edges, const float* __restrict__ bias,
    float* __restrict__ out) {
    int row = (blockIdx.x * blockDim.x + threadIdx.x) >> 6;
    int lane = threadIdx.x & 63;
    if (row >= N_NODES) return;
    int start = rowptr[row], end = rowptr[row + 1];
    const float2* feat2 = (const float2*)feat;
    float ax0 = 0.f, ay0 = 0.f, ax1 = 0.f, ay1 = 0.f;
    float ax2 = 0.f, ay2 = 0.f, ax3 = 0.f, ay3 = 0.f;
    for (int base = start; base < end; base += 64) {
        int n = end - base; if (n > 64) n = 64;
        int2 ev = make_int2(0, 0);
        if (lane < n) ev = edges[base + lane];
        int c = ev.x; float v = __int_as_float(ev.y);
        int j = 0;
        for (; j + 8 <= n; j += 8) {
            int c0 = __shfl(c, j, 64), c1 = __shfl(c, j + 1, 64);
            int c2 = __shfl(c, j + 2, 64), c3 = __shfl(c, j + 3, 64);
            int c4 = __shfl(c, j + 4, 64), c5 = __shfl(c, j + 5, 64);
            int c6 = __shfl(c, j + 6, 64), c7 = __shfl(c, j + 7, 64);
            float v0 = __shfl(v, j, 64), v1 = __shfl(v, j + 1, 64);
            float v2 = __shfl(v, j + 2, 64), v3 = __shfl(v, j + 3, 64);
            float v4 = __shfl(v, j + 4, 64), v5 = __shfl(v, j + 5, 64);
            float v6 = __shfl(v, j + 6, 64), v7 = __shfl(v, j + 7, 64);
            float2 f0 = feat2[(size_t)c0 * 64 + lane];
            float2 f1 = feat2[(size_t)c1 * 64 + lane];
            float2 f2 = feat2[(size_t)c2 * 64 + lane];
            float2 f3 = feat2[(size_t)c3 * 64 + lane];
            float2 f4 = feat2[(size_t)c4 * 64 + lane];
            float2 f5 = feat2[(size_t)c5 * 64 + lane];
            float2 f6 = feat2[(size_t)c6 * 64 + lane];
            float2 f7 = feat2[(size_t)c7 * 64 + lane];
            ax0 += v0 * f0.x; ay0 += v0 * f0.y;
            ax1 += v1 * f1.x; ay1 += v1 * f1.y;
            ax2 += v2 * f2.x; ay2 += v2 * f2.y;
            ax3 += v3 * f3.x; ay3 += v3 * f3.y;
            ax0 += v4 * f4.x; ay0 += v4 * f4.y;
            ax1 += v5 * f5.x; ay1 += v5 * f5.y;
            ax2 += v6 * f6.x; ay2 += v6 * f6.y;
            ax3 += v7 * f7.x; ay3 += v7 * f7.y;
        }
        for (; j + 4 <= n; j += 4) {
            int c0 = __shfl(c, j, 64), c1 = __shfl(c, j + 1, 64);
            int c2 = __shfl(c, j + 2, 64), c3 = __shfl(c, j + 3, 64);
            float v0 = __shfl(v, j, 64), v1 = __shfl(v, j + 1, 64);
            float v2 = __shfl(v, j + 2, 64), v3 = __shfl(v, j + 3, 64);
            float2 f0 = feat2[(size_t)c0 * 64 + lane];
            float2 f1 = feat2[(size_t)c1 * 64 + lane];
            float2 f2 = feat2[(size_t)c2 * 64 + lane];
            float2 f3 = feat2[(size_t)c3 * 64 + lane];
            ax0 += v0 * f0.x; ay0 += v0 * f0.y;
            ax1 += v1 * f1.x; ay1 += v1 * f1.y;
            ax2 += v2 * f2.x; ay2 += v2 * f2.y;
            ax3 += v3 * f3.x; ay3 += v3 * f3.y;
        }
        for (; j < n; j++) {
            int c0 = __shfl(c, j, 64);
            float v0 = __shfl(v, j, 64);
            float2 f0 = feat2[(size_t)c0 * 64 + lane];
            ax0 += v0 * f0.x; ay0 += v0 * f0.y;
        }
    }
    float2 b = ((const float2*)bias)[lane];
    float ax = (ax0 + ax1) + (ax2 + ax3) + b.x;
    float ay = (ay0 + ay1) + (ay2 + ay3) + b.y;
    ((float2*)out)[(size_t)row * 64 + lane] = make_float2(ax, ay);
}

// ---------------------------------------------------------------------------
// bf16 MFMA GEMM: out[n, NOUT] = act(A[n, K] @ B[K, NOUT] + bias)
// Block = 256 thr (4 waves). Tile M=64, N=64, K chunked by 64.
// ---------------------------------------------------------------------------
template <int K, int NOUT, bool RELU, bool OUT_BF16>
__global__ __launch_bounds__(256) void gemm_mfma(
    const ushort16* __restrict__ A, const ushort16* __restrict__ Bw,
    const float* __restrict__ bias, void* __restrict__ outv, int nrows) {
    __shared__ ushort16 a_s[64 * 72];
    __shared__ ushort16 b_s[64 * 72];
    const int tx = threadIdx.x;
    const int wave = tx >> 6, lane = tx & 63;
    const int quad = lane >> 4, l16 = lane & 15;
    const int row0 = blockIdx.x * 64, col0 = blockIdx.y * 64;

    floatx4 acc[4];
    #pragma unroll
    for (int i = 0; i < 4; i++)
        #pragma unroll
        for (int j = 0; j < 4; j++) acc[i][j] = 0.f;

    #pragma unroll
    for (int kc = 0; kc < K / 64; kc++) {
        const uint32* Ag = (const uint32*)A;
        #pragma unroll
        for (int i = 0; i < 8; i++) {
            int idx = tx + i * 256;
            int r = idx >> 5, c = idx & 31;
            uint32 v = 0;
            if (row0 + r < nrows) v = Ag[(size_t)(row0 + r) * (K / 2) + kc * 32 + c];
            *(uint32*)&a_s[r * 72 + c * 2] = v;
        }
        #pragma unroll
        for (int i = 0; i < 16; i++) {
            int idx = tx + i * 256;
            int kr = idx >> 6, nc = idx & 63;
            b_s[nc * 72 + kr] = Bw[(size_t)(kc * 64 + kr) * NOUT + col0 + nc];
        }
        __syncthreads();
        #pragma unroll
        for (int kk = 0; kk < 2; kk++) {
            short8 af = *(const short8*)&a_s[(wave * 16 + l16) * 72 + kk * 32 + quad * 8];
            #pragma unroll
            for (int ct = 0; ct < 4; ct++) {
                short8 bf = *(const short8*)&b_s[(ct * 16 + l16) * 72 + kk * 32 + quad * 8];
                acc[ct] = __builtin_amdgcn_mfma_f32_16x16x32_bf16(af, bf, acc[ct], 0, 0, 0);
            }
        }
        __syncthreads();
    }

    #pragma unroll
    for (int ct = 0; ct < 4; ct++) {
        int col = col0 + ct * 16 + l16;
        float bv = bias ? bias[col] : 0.f;
        #pragma unroll
        for (int reg = 0; reg < 4; reg++) {
            int row = row0 + wave * 16 + quad * 4 + reg;
            if (row < nrows) {
                float val = acc[ct][reg] + bv;
                if (RELU) val = val > 0.f ? val : 0.f;
                if (OUT_BF16)
                    ((ushort16*)outv)[(size_t)row * NOUT + col] = f2bf(val);
                else
                    ((float*)outv)[(size_t)row * NOUT + col] = val;
            }
        }
    }
}

extern "C" void kernel_launch(void* const* d_in, const int* in_sizes, int n_in,
                              void* d_out, int out_size, void* d_ws, size_t ws_size,
                              hipStream_t stream) {
    const float* x = (const float*)d_in[0];
    const float* adj_vals = (const float*)d_in[1];
    const int* adj_row = (const int*)d_in[2];
    const int* adj_col = (const int*)d_in[3];
    const float* W1 = (const float*)d_in[4];
    const float* b1 = (const float*)d_in[5];
    const float* W2 = (const float*)d_in[6];
    const float* b2 = (const float*)d_in[7];
    float* out = (float*)d_out;

    // Workspace layout (~83.8 MB):
    char* ws = (char*)d_ws;
    uint32*   xb       = (uint32*)  (ws + 0);            // 12.8 MB (bf16 x-norm)
    uint32*   agg1     = (uint32*)  (ws + 12800000);     // 12.8 MB (bf16)
    ushort16* h        = (ushort16*)(ws + 25600000);     // 25.6 MB (bf16)
    float*    hw       = (float*)   (ws + 51200000);     // 25.6 MB (fp32)
    int2*     edges    = (int2*)    (ws + 76800000);     //  6.4 MB
    int*      rowptr   = (int*)     (ws + 83200000);     //  200 KB
    int*      cursor   = (int*)     (ws + 83400008);     //  200 KB
    ushort16* W1b      = (ushort16*)(ws + 83600016);     //   64 KB
    ushort16* W2b      = (ushort16*)(ws + 83665552);     //   64 KB
    int*      partials = (int*)     (ws + 83731088);     //  784 B

    // 1. x-hat = bf16(row-normalized x)
    hipLaunchKernelGGL(norm_bf16_kernel, dim3((N_NODES * 64 + 255) / 256), dim3(256),
                       0, stream, x, xb);
    // 2. weights -> bf16
    hipLaunchKernelGGL(convert_w_kernel, dim3((H_DIM * 256 + 255) / 256), dim3(256),
                       0, stream, W1, W2, W1b, W2b);

    // 3. CSR build: histogram -> hierarchical scan -> scatter
    hipMemsetAsync(cursor, 0, (N_NODES + 1) * sizeof(int), stream);
    hipLaunchKernelGGL(hist_kernel, dim3((N_EDGES + 255) / 256), dim3(256),
                       0, stream, adj_row, cursor);
    hipLaunchKernelGGL(scan_partial_kernel, dim3(SCAN_BLOCKS), dim3(256),
                       0, stream, cursor, partials);
    hipLaunchKernelGGL(scan_top_kernel, dim3(1), dim3(256),
                       0, stream, partials, rowptr);
    hipLaunchKernelGGL(scan_apply_kernel, dim3(SCAN_BLOCKS), dim3(256),
                       0, stream, cursor, partials, rowptr);
    hipMemsetAsync(cursor, 0, (N_NODES + 1) * sizeof(int), stream);
    hipLaunchKernelGGL(scatter_kernel, dim3((N_EDGES + 255) / 256), dim3(256),
                       0, stream, adj_row, adj_col, adj_vals, rowptr, cursor, edges);

    // 4. agg1 = A @ x-hat   (bf16 gather, bf16 out)
    hipLaunchKernelGGL(spmm_csr_bf16, dim3((N_NODES * 64 + 255) / 256), dim3(256),
                       0, stream, xb, rowptr, edges, agg1);

    // 5. h = relu(agg1 @ W1 + b1)   [MFMA bf16]
    hipLaunchKernelGGL((gemm_mfma<128, 256, true, true>), dim3((N_NODES + 63) / 64, 4), dim3(256),
                       0, stream, (const ushort16*)agg1, W1b, b1, (void*)h, N_NODES);

    // 6. hw = h @ W2   [MFMA bf16, fp32 out]
    hipLaunchKernelGGL((gemm_mfma<256, 128, false, false>), dim3((N_NODES + 63) / 64, 2), dim3(256),
                       0, stream, h, W2b, (const float*)nullptr, (void*)hw, N_NODES);

    // 7. out = A @ hw + b2   (fp32 gather)
    hipLaunchKernelGGL(spmm_csr_f32, dim3((N_NODES * 64 + 255) / 256), dim3(256),
                       0, stream, hw, rowptr, edges, b2, out);
}

// Round 5
// 315.645 us; speedup vs baseline: 9.2147x; 1.1245x over previous
//
#include <hip/hip_runtime.h>

// Problem constants (fixed by the reference).
#define N_NODES 50000
#define N_EDGES 800000
#define X_DIM 128
#define H_DIM 256
#define Y_DIM 128

typedef unsigned int uint32;
typedef unsigned short ushort16;
typedef __attribute__((ext_vector_type(8))) short short8;
typedef __attribute__((ext_vector_type(4))) float floatx4;

// bf16 helpers (round-to-nearest-even)
__device__ inline ushort16 f2bf(float f) {
    uint32 u = __float_as_uint(f);
    return (ushort16)((u + 0x7FFFu + ((u >> 16) & 1u)) >> 16);
}
__device__ inline float bf_lo(uint32 u) { return __uint_as_float(u << 16); }
__device__ inline float bf_hi(uint32 u) { return __uint_as_float(u & 0xFFFF0000u); }

#define NORM_BLOCKS 12500  // N_NODES*64/256
#define CONV_BLOCKS 256    // 65536/256

// ---------------------------------------------------------------------------
// Prep (fused): row-normalize x -> bf16  AND  transpose-convert W1,W2 to bf16.
// W1t[n][k] (256x128), W2t[y][k] (128x256) so MFMA B-fragments are contiguous.
// ---------------------------------------------------------------------------
__global__ __launch_bounds__(256) void prep_kernel(
    const float* __restrict__ x, uint32* __restrict__ xb,
    const float* __restrict__ W1, const float* __restrict__ W2,
    ushort16* __restrict__ W1t, ushort16* __restrict__ W2t) {
    int b = blockIdx.x;
    if (b < NORM_BLOCKS) {
        int row = (b * 256 + threadIdx.x) >> 6;
        int lane = threadIdx.x & 63;
        if (row >= N_NODES) return;
        float2 v = ((const float2*)x)[(size_t)row * 64 + lane];
        float s = v.x + v.y;
        #pragma unroll
        for (int off = 32; off > 0; off >>= 1) s += __shfl_xor(s, off, 64);
        float inv = 1.0f / (s + 1e-4f);
        uint32 lo = (uint32)f2bf(v.x * inv);
        uint32 hi = (uint32)f2bf(v.y * inv);
        xb[(size_t)row * 64 + lane] = lo | (hi << 16);
    } else {
        int t = (b - NORM_BLOCKS) * 256 + threadIdx.x;  // 0..65535
        if (t < X_DIM * H_DIM) {
            int n = t >> 7, k = t & 127;           // W1t[n][k] = W1[k][n]
            W1t[t] = f2bf(W1[k * H_DIM + n]);
        } else {
            int u = t - X_DIM * H_DIM;
            int y = u >> 8, k = u & 255;           // W2t[y][k] = W2[k][y]
            W2t[u] = f2bf(W2[k * Y_DIM + y]);
        }
    }
}

// ---------------------------------------------------------------------------
// CSR build: histogram -> partial sums -> apply (top-scan fused, zeroes cursor)
// -> scatter
// ---------------------------------------------------------------------------
__global__ __launch_bounds__(256) void hist_kernel(
    const int* __restrict__ rows, int* __restrict__ counts) {
    int e = blockIdx.x * blockDim.x + threadIdx.x;
    if (e < N_EDGES) atomicAdd(&counts[rows[e]], 1);
}

#define SCAN_BLOCKS 196  // ceil(50000/256)

__global__ __launch_bounds__(256) void scan_partial_kernel(
    const int* __restrict__ counts, int* __restrict__ partials) {
    __shared__ int wsum[4];
    int t = threadIdx.x;
    int i = blockIdx.x * 256 + t;
    int s = (i < N_NODES) ? counts[i] : 0;
    #pragma unroll
    for (int off = 32; off > 0; off >>= 1) s += __shfl_down(s, off, 64);
    if ((t & 63) == 0) wsum[t >> 6] = s;
    __syncthreads();
    if (t == 0) partials[blockIdx.x] = wsum[0] + wsum[1] + wsum[2] + wsum[3];
}

// Per-block: block offset = masked reduction of partials[< blockIdx], then
// exclusive scan of own 256-chunk -> rowptr; zero counts (becomes cursor).
__global__ __launch_bounds__(256) void scan_apply_kernel(
    int* __restrict__ counts, const int* __restrict__ partials,
    int* __restrict__ rowptr) {
    __shared__ int red[256];
    __shared__ int part[256];
    int t = threadIdx.x;
    int i = blockIdx.x * 256 + t;
    // block offset (sum of preceding partials; blockIdx <= 195 < 256)
    red[t] = (t < blockIdx.x) ? partials[t] : 0;
    int v = (i < N_NODES) ? counts[i] : 0;
    part[t] = v;
    __syncthreads();
    #pragma unroll
    for (int off = 128; off > 0; off >>= 1) {
        if (t < off) red[t] += red[t + off];
        __syncthreads();
    }
    int block_off = red[0];
    // Hillis-Steele inclusive scan of part[]
    #pragma unroll
    for (int off = 1; off < 256; off <<= 1) {
        int u = (t >= off) ? part[t - off] : 0;
        __syncthreads();
        part[t] += u;
        __syncthreads();
    }
    if (i < N_NODES) {
        rowptr[i] = block_off + part[t] - v;  // exclusive
        counts[i] = 0;                        // cursor for scatter
    }
    if (blockIdx.x == 0 && t == 0) rowptr[N_NODES] = N_EDGES;
}

__global__ __launch_bounds__(256) void scatter_kernel(
    const int* __restrict__ rows, const int* __restrict__ cols,
    const float* __restrict__ vals, const int* __restrict__ rowptr,
    int* __restrict__ cursor, int2* __restrict__ edges) {
    int e = blockIdx.x * blockDim.x + threadIdx.x;
    if (e >= N_EDGES) return;
    int r = rows[e];
    int pos = rowptr[r] + atomicAdd(&cursor[r], 1);
    edges[pos] = make_int2(cols[e], __float_as_int(vals[e]));
}

// ---------------------------------------------------------------------------
// CSR spmm (bf16 feat, D=128). One wave/row, lane owns 2 dims, 8-wide MLP.
// OUT_F32: add bias, write float2 (final layer). Else write packed bf16.
// ---------------------------------------------------------------------------
template <bool OUT_F32>
__global__ __launch_bounds__(256) void spmm_csr_bf16(
    const uint32* __restrict__ feat, const int* __restrict__ rowptr,
    const int2* __restrict__ edges, const float* __restrict__ bias,
    void* __restrict__ outv) {
    int row = (blockIdx.x * blockDim.x + threadIdx.x) >> 6;
    int lane = threadIdx.x & 63;
    if (row >= N_NODES) return;
    int start = rowptr[row], end = rowptr[row + 1];
    float ax0 = 0.f, ay0 = 0.f, ax1 = 0.f, ay1 = 0.f;
    float ax2 = 0.f, ay2 = 0.f, ax3 = 0.f, ay3 = 0.f;
    for (int base = start; base < end; base += 64) {
        int n = end - base; if (n > 64) n = 64;
        int2 ev = make_int2(0, 0);
        if (lane < n) ev = edges[base + lane];
        int c = ev.x; float v = __int_as_float(ev.y);
        int j = 0;
        for (; j + 8 <= n; j += 8) {
            int c0 = __shfl(c, j, 64), c1 = __shfl(c, j + 1, 64);
            int c2 = __shfl(c, j + 2, 64), c3 = __shfl(c, j + 3, 64);
            int c4 = __shfl(c, j + 4, 64), c5 = __shfl(c, j + 5, 64);
            int c6 = __shfl(c, j + 6, 64), c7 = __shfl(c, j + 7, 64);
            float v0 = __shfl(v, j, 64), v1 = __shfl(v, j + 1, 64);
            float v2 = __shfl(v, j + 2, 64), v3 = __shfl(v, j + 3, 64);
            float v4 = __shfl(v, j + 4, 64), v5 = __shfl(v, j + 5, 64);
            float v6 = __shfl(v, j + 6, 64), v7 = __shfl(v, j + 7, 64);
            uint32 f0 = feat[(size_t)c0 * 64 + lane];
            uint32 f1 = feat[(size_t)c1 * 64 + lane];
            uint32 f2 = feat[(size_t)c2 * 64 + lane];
            uint32 f3 = feat[(size_t)c3 * 64 + lane];
            uint32 f4 = feat[(size_t)c4 * 64 + lane];
            uint32 f5 = feat[(size_t)c5 * 64 + lane];
            uint32 f6 = feat[(size_t)c6 * 64 + lane];
            uint32 f7 = feat[(size_t)c7 * 64 + lane];
            ax0 += v0 * bf_lo(f0); ay0 += v0 * bf_hi(f0);
            ax1 += v1 * bf_lo(f1); ay1 += v1 * bf_hi(f1);
            ax2 += v2 * bf_lo(f2); ay2 += v2 * bf_hi(f2);
            ax3 += v3 * bf_lo(f3); ay3 += v3 * bf_hi(f3);
            ax0 += v4 * bf_lo(f4); ay0 += v4 * bf_hi(f4);
            ax1 += v5 * bf_lo(f5); ay1 += v5 * bf_hi(f5);
            ax2 += v6 * bf_lo(f6); ay2 += v6 * bf_hi(f6);
            ax3 += v7 * bf_lo(f7); ay3 += v7 * bf_hi(f7);
        }
        for (; j + 4 <= n; j += 4) {
            int c0 = __shfl(c, j, 64), c1 = __shfl(c, j + 1, 64);
            int c2 = __shfl(c, j + 2, 64), c3 = __shfl(c, j + 3, 64);
            float v0 = __shfl(v, j, 64), v1 = __shfl(v, j + 1, 64);
            float v2 = __shfl(v, j + 2, 64), v3 = __shfl(v, j + 3, 64);
            uint32 f0 = feat[(size_t)c0 * 64 + lane];
            uint32 f1 = feat[(size_t)c1 * 64 + lane];
            uint32 f2 = feat[(size_t)c2 * 64 + lane];
            uint32 f3 = feat[(size_t)c3 * 64 + lane];
            ax0 += v0 * bf_lo(f0); ay0 += v0 * bf_hi(f0);
            ax1 += v1 * bf_lo(f1); ay1 += v1 * bf_hi(f1);
            ax2 += v2 * bf_lo(f2); ay2 += v2 * bf_hi(f2);
            ax3 += v3 * bf_lo(f3); ay3 += v3 * bf_hi(f3);
        }
        for (; j < n; j++) {
            int c0 = __shfl(c, j, 64);
            float v0 = __shfl(v, j, 64);
            uint32 f0 = feat[(size_t)c0 * 64 + lane];
            ax0 += v0 * bf_lo(f0); ay0 += v0 * bf_hi(f0);
        }
    }
    float ax = (ax0 + ax1) + (ax2 + ax3);
    float ay = (ay0 + ay1) + (ay2 + ay3);
    if (OUT_F32) {
        float2 b = ((const float2*)bias)[lane];
        ((float2*)outv)[(size_t)row * 64 + lane] = make_float2(ax + b.x, ay + b.y);
    } else {
        ((uint32*)outv)[(size_t)row * 64 + lane] =
            (uint32)f2bf(ax) | ((uint32)f2bf(ay) << 16);
    }
}

// ---------------------------------------------------------------------------
// Fused MFMA GEMM: hw = relu(agg1 @ W1 + b1) @ W2, per 64-row tile.
// Stage 1: h_tile (64x256) via 16x16x32 bf16 MFMA, B-fragments streamed from
//   W1t (L2-hot, contiguous 16B). Result -> LDS (C-layout -> A-layout round
//   trip, m120 pattern).
// Stage 2: hw_tile (64x128) = h_tile @ W2t, written bf16.
// LDS 51.2 KB -> 3 blocks/CU. Strides 136/264 shorts -> 2-way reads (free).
// ---------------------------------------------------------------------------
__global__ __launch_bounds__(256) void gemm_fused(
    const uint32* __restrict__ agg1, const ushort16* __restrict__ W1t,
    const ushort16* __restrict__ W2t, const float* __restrict__ b1,
    ushort16* __restrict__ hw, int nrows) {
    __shared__ ushort16 a_s[64 * 136];
    __shared__ ushort16 h_s[64 * 264];
    const int tx = threadIdx.x;
    const int wave = tx >> 6, lane = tx & 63;
    const int quad = lane >> 4, l16 = lane & 15;
    const int row0 = blockIdx.x * 64;

    // stage A: 64 rows x 64 uints (bf16x2)
    #pragma unroll
    for (int i = 0; i < 16; i++) {
        int idx = tx + i * 256;
        int r = idx >> 6, c = idx & 63;
        uint32 v = 0;
        if (row0 + r < nrows) v = agg1[(size_t)(row0 + r) * 64 + c];
        *(uint32*)&a_s[r * 136 + c * 2] = v;
    }
    __syncthreads();

    // stage 1: h = relu(A @ W1 + b1)
    floatx4 acc1[16];
    #pragma unroll
    for (int i = 0; i < 16; i++)
        #pragma unroll
        for (int j = 0; j < 4; j++) acc1[i][j] = 0.f;
    #pragma unroll
    for (int kk = 0; kk < 4; kk++) {
        short8 af = *(const short8*)&a_s[(wave * 16 + l16) * 136 + kk * 32 + quad * 8];
        #pragma unroll
        for (int ct = 0; ct < 16; ct++) {
            short8 bf = *(const short8*)&W1t[(ct * 16 + l16) * 128 + kk * 32 + quad * 8];
            acc1[ct] = __builtin_amdgcn_mfma_f32_16x16x32_bf16(af, bf, acc1[ct], 0, 0, 0);
        }
    }
    #pragma unroll
    for (int ct = 0; ct < 16; ct++) {
        float bv = b1[ct * 16 + l16];
        #pragma unroll
        for (int reg = 0; reg < 4; reg++) {
            float v = acc1[ct][reg] + bv;
            v = v > 0.f ? v : 0.f;
            h_s[(wave * 16 + quad * 4 + reg) * 264 + ct * 16 + l16] = f2bf(v);
        }
    }
    __syncthreads();

    // stage 2: hw = h @ W2
    floatx4 acc2[8];
    #pragma unroll
    for (int i = 0; i < 8; i++)
        #pragma unroll
        for (int j = 0; j < 4; j++) acc2[i][j] = 0.f;
    #pragma unroll
    for (int kk = 0; kk < 8; kk++) {
        short8 af = *(const short8*)&h_s[(wave * 16 + l16) * 264 + kk * 32 + quad * 8];
        #pragma unroll
        for (int ct = 0; ct < 8; ct++) {
            short8 bf = *(const short8*)&W2t[(ct * 16 + l16) * 256 + kk * 32 + quad * 8];
            acc2[ct] = __builtin_amdgcn_mfma_f32_16x16x32_bf16(af, bf, acc2[ct], 0, 0, 0);
        }
    }
    #pragma unroll
    for (int ct = 0; ct < 8; ct++) {
        #pragma unroll
        for (int reg = 0; reg < 4; reg++) {
            int row = row0 + wave * 16 + quad * 4 + reg;
            if (row < nrows)
                hw[(size_t)row * 128 + ct * 16 + l16] = f2bf(acc2[ct][reg]);
        }
    }
}

extern "C" void kernel_launch(void* const* d_in, const int* in_sizes, int n_in,
                              void* d_out, int out_size, void* d_ws, size_t ws_size,
                              hipStream_t stream) {
    const float* x = (const float*)d_in[0];
    const float* adj_vals = (const float*)d_in[1];
    const int* adj_row = (const int*)d_in[2];
    const int* adj_col = (const int*)d_in[3];
    const float* W1 = (const float*)d_in[4];
    const float* b1 = (const float*)d_in[5];
    const float* W2 = (const float*)d_in[6];
    const float* b2 = (const float*)d_in[7];
    float* out = (float*)d_out;

    // Workspace layout (~45.3 MB):
    char* ws = (char*)d_ws;
    uint32*   xb       = (uint32*)  (ws + 0);            // 12.8 MB (bf16 x-norm)
    uint32*   agg1     = (uint32*)  (ws + 12800000);     // 12.8 MB (bf16)
    ushort16* hw       = (ushort16*)(ws + 25600000);     // 12.8 MB (bf16)
    int2*     edges    = (int2*)    (ws + 38400000);     //  6.4 MB
    int*      cursor   = (int*)     (ws + 44800000);     //  200 KB (counts/cursor)
    int*      rowptr   = (int*)     (ws + 45000064);     //  200 KB
    int*      partials = (int*)     (ws + 45200128);     //  784 B
    ushort16* W1t      = (ushort16*)(ws + 45201024);     //   64 KB
    ushort16* W2t      = (ushort16*)(ws + 45266560);     //   64 KB

    // 1. prep: x-hat bf16 + transposed bf16 weights
    hipLaunchKernelGGL(prep_kernel, dim3(NORM_BLOCKS + CONV_BLOCKS), dim3(256),
                       0, stream, x, xb, W1, W2, W1t, W2t);

    // 2. CSR build
    hipMemsetAsync(cursor, 0, N_NODES * sizeof(int), stream);
    hipLaunchKernelGGL(hist_kernel, dim3((N_EDGES + 255) / 256), dim3(256),
                       0, stream, adj_row, cursor);
    hipLaunchKernelGGL(scan_partial_kernel, dim3(SCAN_BLOCKS), dim3(256),
                       0, stream, cursor, partials);
    hipLaunchKernelGGL(scan_apply_kernel, dim3(SCAN_BLOCKS), dim3(256),
                       0, stream, cursor, partials, rowptr);
    hipLaunchKernelGGL(scatter_kernel, dim3((N_EDGES + 255) / 256), dim3(256),
                       0, stream, adj_row, adj_col, adj_vals, rowptr, cursor, edges);

    // 3. agg1 = A @ x-hat
    hipLaunchKernelGGL((spmm_csr_bf16<false>), dim3((N_NODES * 64 + 255) / 256), dim3(256),
                       0, stream, xb, rowptr, edges, (const float*)nullptr, (void*)agg1);

    // 4. hw = relu(agg1 @ W1 + b1) @ W2   [fused MFMA]
    hipLaunchKernelGGL(gemm_fused, dim3((N_NODES + 63) / 64), dim3(256),
                       0, stream, agg1, W1t, W2t, b1, hw, N_NODES);

    // 5. out = A @ hw + b2
    hipLaunchKernelGGL((spmm_csr_bf16<true>), dim3((N_NODES * 64 + 255) / 256), dim3(256),
                       0, stream, (const uint32*)hw, rowptr, edges, b2, (void*)out);
}

// Round 7
// 262.335 us; speedup vs baseline: 11.0873x; 1.2032x over previous
//
#include <hip/hip_runtime.h>

// Problem constants (fixed by the reference).
#define N_NODES 50000
#define N_EDGES 800000
#define X_DIM 128
#define H_DIM 256
#define Y_DIM 128

typedef unsigned int uint32;
typedef unsigned short ushort16;
typedef __attribute__((ext_vector_type(8))) short short8;
typedef __attribute__((ext_vector_type(4))) float floatx4;

// bf16 helpers (round-to-nearest-even)
__device__ inline ushort16 f2bf(float f) {
    uint32 u = __float_as_uint(f);
    return (ushort16)((u + 0x7FFFu + ((u >> 16) & 1u)) >> 16);
}
__device__ inline float bf_lo(uint32 u) { return __uint_as_float(u << 16); }
__device__ inline float bf_hi(uint32 u) { return __uint_as_float(u & 0xFFFF0000u); }

#define NORM_BLOCKS 12500  // N_NODES*64/256
#define CONV_BLOCKS 256    // 65536/256
#define ZERO_BLOCKS 196    // ceil(50000/256) - zero the edge-count array

// ---------------------------------------------------------------------------
// Prep (fused): row-normalize x -> bf16; transpose-convert W1,W2 to bf16;
// zero the CSR count array (saves a hipMemsetAsync enqueue).
// W1t[n][k] (256x128), W2t[y][k] (128x256) so MFMA B-fragments are contiguous.
// ---------------------------------------------------------------------------
__global__ __launch_bounds__(256) void prep_kernel(
    const float* __restrict__ x, uint32* __restrict__ xb,
    const float* __restrict__ W1, const float* __restrict__ W2,
    ushort16* __restrict__ W1t, ushort16* __restrict__ W2t,
    int* __restrict__ counts) {
    int b = blockIdx.x;
    if (b < NORM_BLOCKS) {
        int row = (b * 256 + threadIdx.x) >> 6;  // exact: 12500*4 = 50000 rows
        int lane = threadIdx.x & 63;
        float2 v = ((const float2*)x)[(size_t)row * 64 + lane];
        float s = v.x + v.y;
        #pragma unroll
        for (int off = 32; off > 0; off >>= 1) s += __shfl_xor(s, off, 64);
        float inv = 1.0f / (s + 1e-4f);
        uint32 lo = (uint32)f2bf(v.x * inv);
        uint32 hi = (uint32)f2bf(v.y * inv);
        xb[(size_t)row * 64 + lane] = lo | (hi << 16);
    } else if (b < NORM_BLOCKS + CONV_BLOCKS) {
        int t = (b - NORM_BLOCKS) * 256 + threadIdx.x;  // 0..65535
        if (t < X_DIM * H_DIM) {
            int n = t >> 7, k = t & 127;           // W1t[n][k] = W1[k][n]
            W1t[t] = f2bf(W1[k * H_DIM + n]);
        } else {
            int u = t - X_DIM * H_DIM;
            int y = u >> 8, k = u & 255;           // W2t[y][k] = W2[k][y]
            W2t[u] = f2bf(W2[k * Y_DIM + y]);
        }
    } else {
        int i = (b - NORM_BLOCKS - CONV_BLOCKS) * 256 + threadIdx.x;
        if (i < N_NODES) counts[i] = 0;
    }
}

// ---------------------------------------------------------------------------
// CSR build: histogram -> partial sums -> apply (top-scan fused, zeroes cursor)
// -> scatter
// ---------------------------------------------------------------------------
__global__ __launch_bounds__(256) void hist_kernel(
    const int* __restrict__ rows, int* __restrict__ counts) {
    int e = blockIdx.x * blockDim.x + threadIdx.x;
    if (e < N_EDGES) atomicAdd(&counts[rows[e]], 1);
}

#define SCAN_BLOCKS 196  // ceil(50000/256)

__global__ __launch_bounds__(256) void scan_partial_kernel(
    const int* __restrict__ counts, int* __restrict__ partials) {
    __shared__ int wsum[4];
    int t = threadIdx.x;
    int i = blockIdx.x * 256 + t;
    int s = (i < N_NODES) ? counts[i] : 0;
    #pragma unroll
    for (int off = 32; off > 0; off >>= 1) s += __shfl_down(s, off, 64);
    if ((t & 63) == 0) wsum[t >> 6] = s;
    __syncthreads();
    if (t == 0) partials[blockIdx.x] = wsum[0] + wsum[1] + wsum[2] + wsum[3];
}

// Per-block: block offset = masked reduction of partials[< blockIdx], then
// exclusive scan of own 256-chunk -> rowptr; zero counts (becomes cursor).
__global__ __launch_bounds__(256) void scan_apply_kernel(
    int* __restrict__ counts, const int* __restrict__ partials,
    int* __restrict__ rowptr) {
    __shared__ int red[256];
    __shared__ int part[256];
    int t = threadIdx.x;
    int i = blockIdx.x * 256 + t;
    red[t] = (t < blockIdx.x) ? partials[t] : 0;
    int v = (i < N_NODES) ? counts[i] : 0;
    part[t] = v;
    __syncthreads();
    #pragma unroll
    for (int off = 128; off > 0; off >>= 1) {
        if (t < off) red[t] += red[t + off];
        __syncthreads();
    }
    int block_off = red[0];
    #pragma unroll
    for (int off = 1; off < 256; off <<= 1) {
        int u = (t >= off) ? part[t - off] : 0;
        __syncthreads();
        part[t] += u;
        __syncthreads();
    }
    if (i < N_NODES) {
        rowptr[i] = block_off + part[t] - v;  // exclusive
        counts[i] = 0;                        // cursor for scatter
    }
    if (blockIdx.x == 0 && t == 0) rowptr[N_NODES] = N_EDGES;
}

__global__ __launch_bounds__(256) void scatter_kernel(
    const int* __restrict__ rows, const int* __restrict__ cols,
    const float* __restrict__ vals, const int* __restrict__ rowptr,
    int* __restrict__ cursor, int2* __restrict__ edges) {
    int e = blockIdx.x * blockDim.x + threadIdx.x;
    if (e >= N_EDGES) return;
    int r = rows[e];
    int pos = rowptr[r] + atomicAdd(&cursor[r], 1);
    edges[pos] = make_int2(cols[e], __float_as_int(vals[e]));
}

// ---------------------------------------------------------------------------
// CSR spmm (bf16 feat, D=128). One wave/row, lane owns 2 dims, 8-wide MLP.
// OUT_F32: add bias, write float2 (final layer). Else write packed bf16.
// ---------------------------------------------------------------------------
template <bool OUT_F32>
__global__ __launch_bounds__(256) void spmm_csr_bf16(
    const uint32* __restrict__ feat, const int* __restrict__ rowptr,
    const int2* __restrict__ edges, const float* __restrict__ bias,
    void* __restrict__ outv) {
    int row = (blockIdx.x * blockDim.x + threadIdx.x) >> 6;
    int lane = threadIdx.x & 63;
    if (row >= N_NODES) return;
    int start = rowptr[row], end = rowptr[row + 1];
    float ax0 = 0.f, ay0 = 0.f, ax1 = 0.f, ay1 = 0.f;
    float ax2 = 0.f, ay2 = 0.f, ax3 = 0.f, ay3 = 0.f;
    for (int base = start; base < end; base += 64) {
        int n = end - base; if (n > 64) n = 64;
        int2 ev = make_int2(0, 0);
        if (lane < n) ev = edges[base + lane];
        int c = ev.x; float v = __int_as_float(ev.y);
        int j = 0;
        for (; j + 8 <= n; j += 8) {
            int c0 = __shfl(c, j, 64), c1 = __shfl(c, j + 1, 64);
            int c2 = __shfl(c, j + 2, 64), c3 = __shfl(c, j + 3, 64);
            int c4 = __shfl(c, j + 4, 64), c5 = __shfl(c, j + 5, 64);
            int c6 = __shfl(c, j + 6, 64), c7 = __shfl(c, j + 7, 64);
            float v0 = __shfl(v, j, 64), v1 = __shfl(v, j + 1, 64);
            float v2 = __shfl(v, j + 2, 64), v3 = __shfl(v, j + 3, 64);
            float v4 = __shfl(v, j + 4, 64), v5 = __shfl(v, j + 5, 64);
            float v6 = __shfl(v, j + 6, 64), v7 = __shfl(v, j + 7, 64);
            uint32 f0 = feat[(size_t)c0 * 64 + lane];
            uint32 f1 = feat[(size_t)c1 * 64 + lane];
            uint32 f2 = feat[(size_t)c2 * 64 + lane];
            uint32 f3 = feat[(size_t)c3 * 64 + lane];
            uint32 f4 = feat[(size_t)c4 * 64 + lane];
            uint32 f5 = feat[(size_t)c5 * 64 + lane];
            uint32 f6 = feat[(size_t)c6 * 64 + lane];
            uint32 f7 = feat[(size_t)c7 * 64 + lane];
            ax0 += v0 * bf_lo(f0); ay0 += v0 * bf_hi(f0);
            ax1 += v1 * bf_lo(f1); ay1 += v1 * bf_hi(f1);
            ax2 += v2 * bf_lo(f2); ay2 += v2 * bf_hi(f2);
            ax3 += v3 * bf_lo(f3); ay3 += v3 * bf_hi(f3);
            ax0 += v4 * bf_lo(f4); ay0 += v4 * bf_hi(f4);
            ax1 += v5 * bf_lo(f5); ay1 += v5 * bf_hi(f5);
            ax2 += v6 * bf_lo(f6); ay2 += v6 * bf_hi(f6);
            ax3 += v7 * bf_lo(f7); ay3 += v7 * bf_hi(f7);
        }
        for (; j + 4 <= n; j += 4) {
            int c0 = __shfl(c, j, 64), c1 = __shfl(c, j + 1, 64);
            int c2 = __shfl(c, j + 2, 64), c3 = __shfl(c, j + 3, 64);
            float v0 = __shfl(v, j, 64), v1 = __shfl(v, j + 1, 64);
            float v2 = __shfl(v, j + 2, 64), v3 = __shfl(v, j + 3, 64);
            uint32 f0 = feat[(size_t)c0 * 64 + lane];
            uint32 f1 = feat[(size_t)c1 * 64 + lane];
            uint32 f2 = feat[(size_t)c2 * 64 + lane];
            uint32 f3 = feat[(size_t)c3 * 64 + lane];
            ax0 += v0 * bf_lo(f0); ay0 += v0 * bf_hi(f0);
            ax1 += v1 * bf_lo(f1); ay1 += v1 * bf_hi(f1);
            ax2 += v2 * bf_lo(f2); ay2 += v2 * bf_hi(f2);
            ax3 += v3 * bf_lo(f3); ay3 += v3 * bf_hi(f3);
        }
        for (; j < n; j++) {
            int c0 = __shfl(c, j, 64);
            float v0 = __shfl(v, j, 64);
            uint32 f0 = feat[(size_t)c0 * 64 + lane];
            ax0 += v0 * bf_lo(f0); ay0 += v0 * bf_hi(f0);
        }
    }
    float ax = (ax0 + ax1) + (ax2 + ax3);
    float ay = (ay0 + ay1) + (ay2 + ay3);
    if (OUT_F32) {
        float2 b = ((const float2*)bias)[lane];
        ((float2*)outv)[(size_t)row * 64 + lane] = make_float2(ax + b.x, ay + b.y);
    } else {
        ((uint32*)outv)[(size_t)row * 64 + lane] =
            (uint32)f2bf(ax) | ((uint32)f2bf(ay) << 16);
    }
}

// ---------------------------------------------------------------------------
// Fused MFMA GEMM (weight-stationary): hw = relu(agg1 @ W1 + b1) @ W2.
// Per 64-row block, 4 waves. Each wave owns a COLUMN slice (64/256 in stage 1,
// 32/128 in stage 2) across all 4 row-subtiles, so its B-fragments (16 per
// stage, 64 VGPRs) are loaded ONCE up front as independent in-flight loads;
// MFMAs consume register-resident B and LDS-resident A. C->A layout round
// trip through h_s (m120 pattern). LDS 51.2 KB -> 3 blocks/CU.
// R6 bug fixed: A-tile staging is 64 rows x 64 uints = 4096 -> 16 iters.
// ---------------------------------------------------------------------------
__global__ __launch_bounds__(256, 3) void gemm_fused(
    const uint32* __restrict__ agg1, const ushort16* __restrict__ W1t,
    const ushort16* __restrict__ W2t, const float* __restrict__ b1,
    ushort16* __restrict__ hw, int nrows) {
    __shared__ ushort16 a_s[64 * 136];
    __shared__ ushort16 h_s[64 * 264];
    const int tx = threadIdx.x;
    const int wave = tx >> 6, lane = tx & 63;
    const int quad = lane >> 4, l16 = lane & 15;
    const int row0 = blockIdx.x * 64;

    // Preload stage-1 B fragments: wave owns h-cols [wave*64, wave*64+64)
    short8 bfr1[4][4];  // [ct][kk]
    #pragma unroll
    for (int ct = 0; ct < 4; ct++)
        #pragma unroll
        for (int kk = 0; kk < 4; kk++)
            bfr1[ct][kk] = *(const short8*)
                &W1t[(wave * 64 + ct * 16 + l16) * 128 + kk * 32 + quad * 8];

    // stage A tile: 64 rows x 64 uints (bf16x2) = 4096 uints -> 16 iterations
    #pragma unroll
    for (int i = 0; i < 16; i++) {
        int idx = tx + i * 256;
        int r = idx >> 6, c = idx & 63;
        uint32 v = 0;
        if (row0 + r < nrows) v = agg1[(size_t)(row0 + r) * 64 + c];
        *(uint32*)&a_s[r * 136 + c * 2] = v;
    }
    __syncthreads();

    // stage 1: h = relu(A @ W1 + b1); wave covers 4 row-subtiles x 4 col-tiles
    floatx4 acc1[4][4];  // [rs][ct]
    #pragma unroll
    for (int rs = 0; rs < 4; rs++)
        #pragma unroll
        for (int ct = 0; ct < 4; ct++)
            #pragma unroll
            for (int j = 0; j < 4; j++) acc1[rs][ct][j] = 0.f;
    #pragma unroll
    for (int kk = 0; kk < 4; kk++) {
        #pragma unroll
        for (int rs = 0; rs < 4; rs++) {
            short8 af = *(const short8*)&a_s[(rs * 16 + l16) * 136 + kk * 32 + quad * 8];
            #pragma unroll
            for (int ct = 0; ct < 4; ct++)
                acc1[rs][ct] = __builtin_amdgcn_mfma_f32_16x16x32_bf16(
                    af, bfr1[ct][kk], acc1[rs][ct], 0, 0, 0);
        }
    }
    float bv[4];
    #pragma unroll
    for (int ct = 0; ct < 4; ct++) bv[ct] = b1[wave * 64 + ct * 16 + l16];
    #pragma unroll
    for (int rs = 0; rs < 4; rs++)
        #pragma unroll
        for (int ct = 0; ct < 4; ct++)
            #pragma unroll
            for (int reg = 0; reg < 4; reg++) {
                float v = acc1[rs][ct][reg] + bv[ct];
                v = v > 0.f ? v : 0.f;
                h_s[(rs * 16 + quad * 4 + reg) * 264 + wave * 64 + ct * 16 + l16] = f2bf(v);
            }

    // Preload stage-2 B fragments: wave owns hw-cols [wave*32, wave*32+32)
    short8 bfr2[2][8];  // [ct][kk]
    #pragma unroll
    for (int ct = 0; ct < 2; ct++)
        #pragma unroll
        for (int kk = 0; kk < 8; kk++)
            bfr2[ct][kk] = *(const short8*)
                &W2t[(wave * 32 + ct * 16 + l16) * 256 + kk * 32 + quad * 8];
    __syncthreads();

    // stage 2: hw = h @ W2
    floatx4 acc2[4][2];
    #pragma unroll
    for (int rs = 0; rs < 4; rs++)
        #pragma unroll
        for (int ct = 0; ct < 2; ct++)
            #pragma unroll
            for (int j = 0; j < 4; j++) acc2[rs][ct][j] = 0.f;
    #pragma unroll
    for (int kk = 0; kk < 8; kk++) {
        #pragma unroll
        for (int rs = 0; rs < 4; rs++) {
            short8 af = *(const short8*)&h_s[(rs * 16 + l16) * 264 + kk * 32 + quad * 8];
            #pragma unroll
            for (int ct = 0; ct < 2; ct++)
                acc2[rs][ct] = __builtin_amdgcn_mfma_f32_16x16x32_bf16(
                    af, bfr2[ct][kk], acc2[rs][ct], 0, 0, 0);
        }
    }
    #pragma unroll
    for (int rs = 0; rs < 4; rs++)
        #pragma unroll
        for (int ct = 0; ct < 2; ct++)
            #pragma unroll
            for (int reg = 0; reg < 4; reg++) {
                int row = row0 + rs * 16 + quad * 4 + reg;
                if (row < nrows)
                    hw[(size_t)row * 128 + wave * 32 + ct * 16 + l16] =
                        f2bf(acc2[rs][ct][reg]);
            }
}

extern "C" void kernel_launch(void* const* d_in, const int* in_sizes, int n_in,
                              void* d_out, int out_size, void* d_ws, size_t ws_size,
                              hipStream_t stream) {
    const float* x = (const float*)d_in[0];
    const float* adj_vals = (const float*)d_in[1];
    const int* adj_row = (const int*)d_in[2];
    const int* adj_col = (const int*)d_in[3];
    const float* W1 = (const float*)d_in[4];
    const float* b1 = (const float*)d_in[5];
    const float* W2 = (const float*)d_in[6];
    const float* b2 = (const float*)d_in[7];
    float* out = (float*)d_out;

    // Workspace layout (~45.3 MB):
    char* ws = (char*)d_ws;
    uint32*   xb       = (uint32*)  (ws + 0);            // 12.8 MB (bf16 x-norm)
    uint32*   agg1     = (uint32*)  (ws + 12800000);     // 12.8 MB (bf16)
    ushort16* hw       = (ushort16*)(ws + 25600000);     // 12.8 MB (bf16)
    int2*     edges    = (int2*)    (ws + 38400000);     //  6.4 MB
    int*      cursor   = (int*)     (ws + 44800000);     //  200 KB (counts/cursor)
    int*      rowptr   = (int*)     (ws + 45000064);     //  200 KB
    int*      partials = (int*)     (ws + 45200128);     //  784 B
    ushort16* W1t      = (ushort16*)(ws + 45201024);     //   64 KB
    ushort16* W2t      = (ushort16*)(ws + 45266560);     //   64 KB

    // 1. prep: x-hat bf16 + transposed bf16 weights + zeroed counts
    hipLaunchKernelGGL(prep_kernel, dim3(NORM_BLOCKS + CONV_BLOCKS + ZERO_BLOCKS),
                       dim3(256), 0, stream, x, xb, W1, W2, W1t, W2t, cursor);

    // 2. CSR build
    hipLaunchKernelGGL(hist_kernel, dim3((N_EDGES + 255) / 256), dim3(256),
                       0, stream, adj_row, cursor);
    hipLaunchKernelGGL(scan_partial_kernel, dim3(SCAN_BLOCKS), dim3(256),
                       0, stream, cursor, partials);
    hipLaunchKernelGGL(scan_apply_kernel, dim3(SCAN_BLOCKS), dim3(256),
                       0, stream, cursor, partials, rowptr);
    hipLaunchKernelGGL(scatter_kernel, dim3((N_EDGES + 255) / 256), dim3(256),
                       0, stream, adj_row, adj_col, adj_vals, rowptr, cursor, edges);

    // 3. agg1 = A @ x-hat
    hipLaunchKernelGGL((spmm_csr_bf16<false>), dim3((N_NODES * 64 + 255) / 256), dim3(256),
                       0, stream, xb, rowptr, edges, (const float*)nullptr, (void*)agg1);

    // 4. hw = relu(agg1 @ W1 + b1) @ W2   [fused MFMA, weight-stationary]
    hipLaunchKernelGGL(gemm_fused, dim3((N_NODES + 63) / 64), dim3(256),
                       0, stream, agg1, W1t, W2t, b1, hw, N_NODES);

    // 5. out = A @ hw + b2
    hipLaunchKernelGGL((spmm_csr_bf16<true>), dim3((N_NODES * 64 + 255) / 256), dim3(256),
                       0, stream, (const uint32*)hw, rowptr, edges, b2, (void*)out);
}

// Round 8
// 252.973 us; speedup vs baseline: 11.4976x; 1.0370x over previous
//
#include <hip/hip_runtime.h>

// Problem constants (fixed by the reference).
#define N_NODES 50000
#define N_EDGES 800000
#define X_DIM 128
#define H_DIM 256
#define Y_DIM 128

typedef unsigned int uint32;
typedef unsigned short ushort16;
typedef __attribute__((ext_vector_type(8))) short short8;
typedef __attribute__((ext_vector_type(4))) float floatx4;

// bf16 helpers (round-to-nearest-even)
__device__ inline ushort16 f2bf(float f) {
    uint32 u = __float_as_uint(f);
    return (ushort16)((u + 0x7FFFu + ((u >> 16) & 1u)) >> 16);
}
__device__ inline float bf_lo(uint32 u) { return __uint_as_float(u << 16); }
__device__ inline float bf_hi(uint32 u) { return __uint_as_float(u & 0xFFFF0000u); }

#define NORM_BLOCKS 12500  // N_NODES*64/256
#define CONV_BLOCKS 256    // 65536/256
#define ZERO_BLOCKS 196    // ceil(50000/256) - zero the edge-count array

// Bucket sort geometry: 391 buckets of 128 rows each.
#define BUCKET_SHIFT 7
#define NB 391             // ceil(50000/128)
#define PASSA_CHUNK 8192
#define PASSA_BLOCKS 98    // ceil(800000/8192)
#define CAP_B 2560         // LDS capacity per bucket (mean 2046, sigma ~45)

// ---------------------------------------------------------------------------
// Prep (fused): row-normalize x -> bf16; transpose-convert W1,W2 to bf16;
// zero the CSR count array.
// ---------------------------------------------------------------------------
__global__ __launch_bounds__(256) void prep_kernel(
    const float* __restrict__ x, uint32* __restrict__ xb,
    const float* __restrict__ W1, const float* __restrict__ W2,
    ushort16* __restrict__ W1t, ushort16* __restrict__ W2t,
    int* __restrict__ counts) {
    int b = blockIdx.x;
    if (b < NORM_BLOCKS) {
        int row = (b * 256 + threadIdx.x) >> 6;  // exact: 12500*4 = 50000 rows
        int lane = threadIdx.x & 63;
        float2 v = ((const float2*)x)[(size_t)row * 64 + lane];
        float s = v.x + v.y;
        #pragma unroll
        for (int off = 32; off > 0; off >>= 1) s += __shfl_xor(s, off, 64);
        float inv = 1.0f / (s + 1e-4f);
        uint32 lo = (uint32)f2bf(v.x * inv);
        uint32 hi = (uint32)f2bf(v.y * inv);
        xb[(size_t)row * 64 + lane] = lo | (hi << 16);
    } else if (b < NORM_BLOCKS + CONV_BLOCKS) {
        int t = (b - NORM_BLOCKS) * 256 + threadIdx.x;  // 0..65535
        if (t < X_DIM * H_DIM) {
            int n = t >> 7, k = t & 127;           // W1t[n][k] = W1[k][n]
            W1t[t] = f2bf(W1[k * H_DIM + n]);
        } else {
            int u = t - X_DIM * H_DIM;
            int y = u >> 8, k = u & 255;           // W2t[y][k] = W2[k][y]
            W2t[u] = f2bf(W2[k * Y_DIM + y]);
        }
    } else {
        int i = (b - NORM_BLOCKS - CONV_BLOCKS) * 256 + threadIdx.x;
        if (i < N_NODES) counts[i] = 0;
    }
}

// ---------------------------------------------------------------------------
// CSR rowptr build: histogram -> partial sums -> apply.
// ---------------------------------------------------------------------------
__global__ __launch_bounds__(256) void hist_kernel(
    const int* __restrict__ rows, int* __restrict__ counts) {
    int e = blockIdx.x * blockDim.x + threadIdx.x;
    if (e < N_EDGES) atomicAdd(&counts[rows[e]], 1);
}

#define SCAN_BLOCKS 196  // ceil(50000/256)

__global__ __launch_bounds__(256) void scan_partial_kernel(
    const int* __restrict__ counts, int* __restrict__ partials) {
    __shared__ int wsum[4];
    int t = threadIdx.x;
    int i = blockIdx.x * 256 + t;
    int s = (i < N_NODES) ? counts[i] : 0;
    #pragma unroll
    for (int off = 32; off > 0; off >>= 1) s += __shfl_down(s, off, 64);
    if ((t & 63) == 0) wsum[t >> 6] = s;
    __syncthreads();
    if (t == 0) partials[blockIdx.x] = wsum[0] + wsum[1] + wsum[2] + wsum[3];
}

// Per-block: offset = reduction of preceding partials, exclusive scan of own
// chunk -> rowptr. Also seeds bucket_cursor[b] = rowptr[b<<7] for pass A.
__global__ __launch_bounds__(256) void scan_apply_kernel(
    const int* __restrict__ counts, const int* __restrict__ partials,
    int* __restrict__ rowptr, int* __restrict__ bucket_cursor) {
    __shared__ int red[256];
    __shared__ int part[256];
    int t = threadIdx.x;
    int i = blockIdx.x * 256 + t;
    red[t] = (t < blockIdx.x) ? partials[t] : 0;
    int v = (i < N_NODES) ? counts[i] : 0;
    part[t] = v;
    __syncthreads();
    #pragma unroll
    for (int off = 128; off > 0; off >>= 1) {
        if (t < off) red[t] += red[t + off];
        __syncthreads();
    }
    int block_off = red[0];
    #pragma unroll
    for (int off = 1; off < 256; off <<= 1) {
        int u = (t >= off) ? part[t - off] : 0;
        __syncthreads();
        part[t] += u;
        __syncthreads();
    }
    if (i < N_NODES) {
        int rp = block_off + part[t] - v;  // exclusive
        rowptr[i] = rp;
        if ((i & 127) == 0) bucket_cursor[i >> BUCKET_SHIFT] = rp;
    }
    if (blockIdx.x == 0 && t == 0) rowptr[N_NODES] = N_EDGES;
}

// ---------------------------------------------------------------------------
// Pass A: bucketize edges into 391 coarse row-buckets with COALESCED writes.
// Per block: LDS histogram -> scan -> compact into LDS runs -> one global
// atomicAdd per bucket reserves a contiguous range -> copy runs out.
// Edge payload: word0 = col(16) | lrow(7) | bucket(9), word1 = fp32 val.
// ---------------------------------------------------------------------------
__global__ __launch_bounds__(512) void bucketize_kernel(
    const int* __restrict__ rows, const int* __restrict__ cols,
    const float* __restrict__ vals, int* __restrict__ bucket_cursor,
    int2* __restrict__ edges) {
    __shared__ int h[512];        // counts (padded to 512), then inclusive scan
    __shared__ int o[512];        // exclusive offsets
    __shared__ int c[NB];         // local placement cursor
    __shared__ int g[NB];         // reserved global base
    __shared__ int2 buf[PASSA_CHUNK];  // 64 KB
    int t = threadIdx.x;
    int base = blockIdx.x * PASSA_CHUNK;
    int M = N_EDGES - base; if (M > PASSA_CHUNK) M = PASSA_CHUNK;
    h[t] = 0;
    __syncthreads();
    #pragma unroll
    for (int k = 0; k < PASSA_CHUNK / 512; k++) {
        int e = base + t + k * 512;
        if (e < N_EDGES) atomicAdd(&h[rows[e] >> BUCKET_SHIFT], 1);
    }
    __syncthreads();
    int val = h[t];  // original count of bucket t
    #pragma unroll
    for (int off = 1; off < 512; off <<= 1) {
        int u = (t >= off) ? h[t - off] : 0;
        __syncthreads();
        h[t] += u;
        __syncthreads();
    }
    o[t] = h[t] - val;  // exclusive prefix
    if (t < NB) {
        c[t] = 0;
        g[t] = (val > 0) ? atomicAdd(&bucket_cursor[t], val) : 0;
    }
    __syncthreads();
    #pragma unroll
    for (int k = 0; k < PASSA_CHUNK / 512; k++) {
        int e = base + t + k * 512;
        if (e < N_EDGES) {
            int r = rows[e];
            int b = r >> BUCKET_SHIFT;
            int p = o[b] + atomicAdd(&c[b], 1);
            buf[p] = make_int2(cols[e] | ((r & 127) << 16) | (b << 23),
                               __float_as_int(vals[e]));
        }
    }
    __syncthreads();
    for (int i = t; i < M; i += 512) {
        int2 e = buf[i];
        int b = (int)((uint32)e.x >> 23);
        edges[g[b] + (i - o[b])] = e;
    }
}

// ---------------------------------------------------------------------------
// Pass B: sort each bucket's region by row, IN PLACE, via LDS counting sort.
// All global reads/writes coalesced. Fallback through global scratch if a
// bucket exceeds LDS capacity (statistically impossible here, kept for safety).
// ---------------------------------------------------------------------------
__global__ __launch_bounds__(256) void bucket_sort_kernel(
    const int* __restrict__ rowptr, int2* __restrict__ edges,
    int2* __restrict__ scratch) {
    __shared__ int2 buf[CAP_B];   // 20.5 KB
    __shared__ int2 buf2[CAP_B];  // 20.5 KB
    __shared__ int h[128], o[128], c[128];
    int b = blockIdx.x, t = threadIdx.x;
    int base = rowptr[b << BUCKET_SHIFT];
    int hi = (b + 1) << BUCKET_SHIFT; if (hi > N_NODES) hi = N_NODES;
    int cnt = rowptr[hi] - base;
    bool fits = (cnt <= CAP_B);
    if (t < 128) h[t] = 0;
    __syncthreads();
    for (int i = t; i < cnt; i += 256) {
        int2 e = edges[base + i];
        if (fits) buf[i] = e; else scratch[base + i] = e;
        atomicAdd(&h[(e.x >> 16) & 127], 1);
    }
    __syncthreads();
    int valh = (t < 128) ? h[t] : 0;
    #pragma unroll
    for (int off = 1; off < 128; off <<= 1) {
        int u = (t >= off && t < 128) ? h[t - off] : 0;
        __syncthreads();
        if (t < 128) h[t] += u;
        __syncthreads();
    }
    if (t < 128) { o[t] = h[t] - valh; c[t] = 0; }
    __syncthreads();
    for (int i = t; i < cnt; i += 256) {
        int2 e = fits ? buf[i] : scratch[base + i];
        int lr = (e.x >> 16) & 127;
        int p = o[lr] + atomicAdd(&c[lr], 1);
        if (fits) buf2[p] = e; else edges[base + p] = e;
    }
    __syncthreads();
    if (fits)
        for (int i = t; i < cnt; i += 256) edges[base + i] = buf2[i];
}

// ---------------------------------------------------------------------------
// CSR spmm (bf16 feat, D=128). One wave/row, lane owns 2 dims, 8-wide MLP.
// col is the low 16 bits of the packed edge word.
// ---------------------------------------------------------------------------
template <bool OUT_F32>
__global__ __launch_bounds__(256) void spmm_csr_bf16(
    const uint32* __restrict__ feat, const int* __restrict__ rowptr,
    const int2* __restrict__ edges, const float* __restrict__ bias,
    void* __restrict__ outv) {
    int row = (blockIdx.x * blockDim.x + threadIdx.x) >> 6;
    int lane = threadIdx.x & 63;
    if (row >= N_NODES) return;
    int start = rowptr[row], end = rowptr[row + 1];
    float ax0 = 0.f, ay0 = 0.f, ax1 = 0.f, ay1 = 0.f;
    float ax2 = 0.f, ay2 = 0.f, ax3 = 0.f, ay3 = 0.f;
    for (int base = start; base < end; base += 64) {
        int n = end - base; if (n > 64) n = 64;
        int2 ev = make_int2(0, 0);
        if (lane < n) ev = edges[base + lane];
        int c = ev.x & 0xFFFF; float v = __int_as_float(ev.y);
        int j = 0;
        for (; j + 8 <= n; j += 8) {
            int c0 = __shfl(c, j, 64), c1 = __shfl(c, j + 1, 64);
            int c2 = __shfl(c, j + 2, 64), c3 = __shfl(c, j + 3, 64);
            int c4 = __shfl(c, j + 4, 64), c5 = __shfl(c, j + 5, 64);
            int c6 = __shfl(c, j + 6, 64), c7 = __shfl(c, j + 7, 64);
            float v0 = __shfl(v, j, 64), v1 = __shfl(v, j + 1, 64);
            float v2 = __shfl(v, j + 2, 64), v3 = __shfl(v, j + 3, 64);
            float v4 = __shfl(v, j + 4, 64), v5 = __shfl(v, j + 5, 64);
            float v6 = __shfl(v, j + 6, 64), v7 = __shfl(v, j + 7, 64);
            uint32 f0 = feat[(size_t)c0 * 64 + lane];
            uint32 f1 = feat[(size_t)c1 * 64 + lane];
            uint32 f2 = feat[(size_t)c2 * 64 + lane];
            uint32 f3 = feat[(size_t)c3 * 64 + lane];
            uint32 f4 = feat[(size_t)c4 * 64 + lane];
            uint32 f5 = feat[(size_t)c5 * 64 + lane];
            uint32 f6 = feat[(size_t)c6 * 64 + lane];
            uint32 f7 = feat[(size_t)c7 * 64 + lane];
            ax0 += v0 * bf_lo(f0); ay0 += v0 * bf_hi(f0);
            ax1 += v1 * bf_lo(f1); ay1 += v1 * bf_hi(f1);
            ax2 += v2 * bf_lo(f2); ay2 += v2 * bf_hi(f2);
            ax3 += v3 * bf_lo(f3); ay3 += v3 * bf_hi(f3);
            ax0 += v4 * bf_lo(f4); ay0 += v4 * bf_hi(f4);
            ax1 += v5 * bf_lo(f5); ay1 += v5 * bf_hi(f5);
            ax2 += v6 * bf_lo(f6); ay2 += v6 * bf_hi(f6);
            ax3 += v7 * bf_lo(f7); ay3 += v7 * bf_hi(f7);
        }
        for (; j + 4 <= n; j += 4) {
            int c0 = __shfl(c, j, 64), c1 = __shfl(c, j + 1, 64);
            int c2 = __shfl(c, j + 2, 64), c3 = __shfl(c, j + 3, 64);
            float v0 = __shfl(v, j, 64), v1 = __shfl(v, j + 1, 64);
            float v2 = __shfl(v, j + 2, 64), v3 = __shfl(v, j + 3, 64);
            uint32 f0 = feat[(size_t)c0 * 64 + lane];
            uint32 f1 = feat[(size_t)c1 * 64 + lane];
            uint32 f2 = feat[(size_t)c2 * 64 + lane];
            uint32 f3 = feat[(size_t)c3 * 64 + lane];
            ax0 += v0 * bf_lo(f0); ay0 += v0 * bf_hi(f0);
            ax1 += v1 * bf_lo(f1); ay1 += v1 * bf_hi(f1);
            ax2 += v2 * bf_lo(f2); ay2 += v2 * bf_hi(f2);
            ax3 += v3 * bf_lo(f3); ay3 += v3 * bf_hi(f3);
        }
        for (; j < n; j++) {
            int c0 = __shfl(c, j, 64);
            float v0 = __shfl(v, j, 64);
            uint32 f0 = feat[(size_t)c0 * 64 + lane];
            ax0 += v0 * bf_lo(f0); ay0 += v0 * bf_hi(f0);
        }
    }
    float ax = (ax0 + ax1) + (ax2 + ax3);
    float ay = (ay0 + ay1) + (ay2 + ay3);
    if (OUT_F32) {
        float2 b = ((const float2*)bias)[lane];
        ((float2*)outv)[(size_t)row * 64 + lane] = make_float2(ax + b.x, ay + b.y);
    } else {
        ((uint32*)outv)[(size_t)row * 64 + lane] =
            (uint32)f2bf(ax) | ((uint32)f2bf(ay) << 16);
    }
}

// ---------------------------------------------------------------------------
// Fused MFMA GEMM (weight-stationary): hw = relu(agg1 @ W1 + b1) @ W2.
// ---------------------------------------------------------------------------
__global__ __launch_bounds__(256, 3) void gemm_fused(
    const uint32* __restrict__ agg1, const ushort16* __restrict__ W1t,
    const ushort16* __restrict__ W2t, const float* __restrict__ b1,
    ushort16* __restrict__ hw, int nrows) {
    __shared__ ushort16 a_s[64 * 136];
    __shared__ ushort16 h_s[64 * 264];
    const int tx = threadIdx.x;
    const int wave = tx >> 6, lane = tx & 63;
    const int quad = lane >> 4, l16 = lane & 15;
    const int row0 = blockIdx.x * 64;

    short8 bfr1[4][4];  // [ct][kk]
    #pragma unroll
    for (int ct = 0; ct < 4; ct++)
        #pragma unroll
        for (int kk = 0; kk < 4; kk++)
            bfr1[ct][kk] = *(const short8*)
                &W1t[(wave * 64 + ct * 16 + l16) * 128 + kk * 32 + quad * 8];

    #pragma unroll
    for (int i = 0; i < 16; i++) {
        int idx = tx + i * 256;
        int r = idx >> 6, c = idx & 63;
        uint32 v = 0;
        if (row0 + r < nrows) v = agg1[(size_t)(row0 + r) * 64 + c];
        *(uint32*)&a_s[r * 136 + c * 2] = v;
    }
    __syncthreads();

    floatx4 acc1[4][4];  // [rs][ct]
    #pragma unroll
    for (int rs = 0; rs < 4; rs++)
        #pragma unroll
        for (int ct = 0; ct < 4; ct++)
            #pragma unroll
            for (int j = 0; j < 4; j++) acc1[rs][ct][j] = 0.f;
    #pragma unroll
    for (int kk = 0; kk < 4; kk++) {
        #pragma unroll
        for (int rs = 0; rs < 4; rs++) {
            short8 af = *(const short8*)&a_s[(rs * 16 + l16) * 136 + kk * 32 + quad * 8];
            #pragma unroll
            for (int ct = 0; ct < 4; ct++)
                acc1[rs][ct] = __builtin_amdgcn_mfma_f32_16x16x32_bf16(
                    af, bfr1[ct][kk], acc1[rs][ct], 0, 0, 0);
        }
    }
    float bv[4];
    #pragma unroll
    for (int ct = 0; ct < 4; ct++) bv[ct] = b1[wave * 64 + ct * 16 + l16];
    #pragma unroll
    for (int rs = 0; rs < 4; rs++)
        #pragma unroll
        for (int ct = 0; ct < 4; ct++)
            #pragma unroll
            for (int reg = 0; reg < 4; reg++) {
                float v = acc1[rs][ct][reg] + bv[ct];
                v = v > 0.f ? v : 0.f;
                h_s[(rs * 16 + quad * 4 + reg) * 264 + wave * 64 + ct * 16 + l16] = f2bf(v);
            }

    short8 bfr2[2][8];  // [ct][kk]
    #pragma unroll
    for (int ct = 0; ct < 2; ct++)
        #pragma unroll
        for (int kk = 0; kk < 8; kk++)
            bfr2[ct][kk] = *(const short8*)
                &W2t[(wave * 32 + ct * 16 + l16) * 256 + kk * 32 + quad * 8];
    __syncthreads();

    floatx4 acc2[4][2];
    #pragma unroll
    for (int rs = 0; rs < 4; rs++)
        #pragma unroll
        for (int ct = 0; ct < 2; ct++)
            #pragma unroll
            for (int j = 0; j < 4; j++) acc2[rs][ct][j] = 0.f;
    #pragma unroll
    for (int kk = 0; kk < 8; kk++) {
        #pragma unroll
        for (int rs = 0; rs < 4; rs++) {
            short8 af = *(const short8*)&h_s[(rs * 16 + l16) * 264 + kk * 32 + quad * 8];
            #pragma unroll
            for (int ct = 0; ct < 2; ct++)
                acc2[rs][ct] = __builtin_amdgcn_mfma_f32_16x16x32_bf16(
                    af, bfr2[ct][kk], acc2[rs][ct], 0, 0, 0);
        }
    }
    #pragma unroll
    for (int rs = 0; rs < 4; rs++)
        #pragma unroll
        for (int ct = 0; ct < 2; ct++)
            #pragma unroll
            for (int reg = 0; reg < 4; reg++) {
                int row = row0 + rs * 16 + quad * 4 + reg;
                if (row < nrows)
                    hw[(size_t)row * 128 + wave * 32 + ct * 16 + l16] =
                        f2bf(acc2[rs][ct][reg]);
            }
}

extern "C" void kernel_launch(void* const* d_in, const int* in_sizes, int n_in,
                              void* d_out, int out_size, void* d_ws, size_t ws_size,
                              hipStream_t stream) {
    const float* x = (const float*)d_in[0];
    const float* adj_vals = (const float*)d_in[1];
    const int* adj_row = (const int*)d_in[2];
    const int* adj_col = (const int*)d_in[3];
    const float* W1 = (const float*)d_in[4];
    const float* b1 = (const float*)d_in[5];
    const float* W2 = (const float*)d_in[6];
    const float* b2 = (const float*)d_in[7];
    float* out = (float*)d_out;

    // Workspace layout (~51.7 MB):
    char* ws = (char*)d_ws;
    uint32*   xb       = (uint32*)  (ws + 0);            // 12.8 MB (bf16 x-norm)
    uint32*   agg1     = (uint32*)  (ws + 12800000);     // 12.8 MB (bf16)
    ushort16* hw       = (ushort16*)(ws + 25600000);     // 12.8 MB (bf16)
    int2*     edges    = (int2*)    (ws + 38400000);     //  6.4 MB
    int2*     scratch  = (int2*)    (ws + 44800000);     //  6.4 MB (fallback only)
    int*      counts   = (int*)     (ws + 51200000);     //  200 KB
    int*      rowptr   = (int*)     (ws + 51400192);     //  200 KB
    int*      partials = (int*)     (ws + 51600896);     //  784 B
    int*      bcursor  = (int*)     (ws + 51601792);     // 1564 B
    ushort16* W1t      = (ushort16*)(ws + 51603456);     //   64 KB
    ushort16* W2t      = (ushort16*)(ws + 51668992);     //   64 KB

    // 1. prep: x-hat bf16 + transposed bf16 weights + zeroed counts
    hipLaunchKernelGGL(prep_kernel, dim3(NORM_BLOCKS + CONV_BLOCKS + ZERO_BLOCKS),
                       dim3(256), 0, stream, x, xb, W1, W2, W1t, W2t, counts);

    // 2. rowptr build
    hipLaunchKernelGGL(hist_kernel, dim3((N_EDGES + 255) / 256), dim3(256),
                       0, stream, adj_row, counts);
    hipLaunchKernelGGL(scan_partial_kernel, dim3(SCAN_BLOCKS), dim3(256),
                       0, stream, counts, partials);
    hipLaunchKernelGGL(scan_apply_kernel, dim3(SCAN_BLOCKS), dim3(256),
                       0, stream, counts, partials, rowptr, bcursor);

    // 3. edge sort: coarse bucketize (coalesced) + per-bucket LDS sort
    hipLaunchKernelGGL(bucketize_kernel, dim3(PASSA_BLOCKS), dim3(512),
                       0, stream, adj_row, adj_col, adj_vals, bcursor, edges);
    hipLaunchKernelGGL(bucket_sort_kernel, dim3(NB), dim3(256),
                       0, stream, rowptr, edges, scratch);

    // 4. agg1 = A @ x-hat
    hipLaunchKernelGGL((spmm_csr_bf16<false>), dim3((N_NODES * 64 + 255) / 256), dim3(256),
                       0, stream, xb, rowptr, edges, (const float*)nullptr, (void*)agg1);

    // 5. hw = relu(agg1 @ W1 + b1) @ W2   [fused MFMA, weight-stationary]
    hipLaunchKernelGGL(gemm_fused, dim3((N_NODES + 63) / 64), dim3(256),
                       0, stream, agg1, W1t, W2t, b1, hw, N_NODES);

    // 6. out = A @ hw + b2
    hipLaunchKernelGGL((spmm_csr_bf16<true>), dim3((N_NODES * 64 + 255) / 256), dim3(256),
                       0, stream, (const uint32*)hw, rowptr, edges, b2, (void*)out);
}

// Round 9
// 223.757 us; speedup vs baseline: 12.9989x; 1.1306x over previous
//
#include <hip/hip_runtime.h>

// Problem constants (fixed by the reference).
#define N_NODES 50000
#define N_EDGES 800000
#define X_DIM 128
#define H_DIM 256
#define Y_DIM 128

typedef unsigned int uint32;
typedef unsigned short ushort16;
typedef __attribute__((ext_vector_type(8))) short short8;
typedef __attribute__((ext_vector_type(4))) float floatx4;

// bf16 helpers (round-to-nearest-even)
__device__ inline ushort16 f2bf(float f) {
    uint32 u = __float_as_uint(f);
    return (ushort16)((u + 0x7FFFu + ((u >> 16) & 1u)) >> 16);
}
__device__ inline float bf_lo(uint32 u) { return __uint_as_float(u << 16); }
__device__ inline float bf_hi(uint32 u) { return __uint_as_float(u & 0xFFFF0000u); }

// Bucket geometry: 391 buckets of 128 rows; 196 chunks of 4096 edges.
#define BUCKET_SHIFT 7
#define NB 391              // ceil(50000/128)
#define CHUNK 4096
#define NCHUNK 196          // ceil(800000/4096)
#define CAP_B 2560          // LDS capacity per bucket (mean 2046)

#define NORM_BLOCKS 12500   // N_NODES*64/256
#define CONV_BLOCKS 256     // 65536/256

// ---------------------------------------------------------------------------
// Prep (fused): row-normalize x -> bf16; transpose-convert W1,W2 to bf16;
// per-chunk bucket histograms -> gpartial[chunk][bucket] (no global atomics).
// ---------------------------------------------------------------------------
__global__ __launch_bounds__(256) void prep_kernel(
    const float* __restrict__ x, uint32* __restrict__ xb,
    const float* __restrict__ W1, const float* __restrict__ W2,
    ushort16* __restrict__ W1t, ushort16* __restrict__ W2t,
    const int* __restrict__ rows, int* __restrict__ gpartial) {
    int b = blockIdx.x;
    if (b < NORM_BLOCKS) {
        int row = (b * 256 + threadIdx.x) >> 6;  // exact: 12500*4 = 50000 rows
        int lane = threadIdx.x & 63;
        float2 v = ((const float2*)x)[(size_t)row * 64 + lane];
        float s = v.x + v.y;
        #pragma unroll
        for (int off = 32; off > 0; off >>= 1) s += __shfl_xor(s, off, 64);
        float inv = 1.0f / (s + 1e-4f);
        uint32 lo = (uint32)f2bf(v.x * inv);
        uint32 hi = (uint32)f2bf(v.y * inv);
        xb[(size_t)row * 64 + lane] = lo | (hi << 16);
    } else if (b < NORM_BLOCKS + CONV_BLOCKS) {
        int t = (b - NORM_BLOCKS) * 256 + threadIdx.x;  // 0..65535
        if (t < X_DIM * H_DIM) {
            int n = t >> 7, k = t & 127;           // W1t[n][k] = W1[k][n]
            W1t[t] = f2bf(W1[k * H_DIM + n]);
        } else {
            int u = t - X_DIM * H_DIM;
            int y = u >> 8, k = u & 255;           // W2t[y][k] = W2[k][y]
            W2t[u] = f2bf(W2[k * Y_DIM + y]);
        }
    } else {
        __shared__ int h[NB];
        int j = b - NORM_BLOCKS - CONV_BLOCKS;     // chunk id 0..195
        int t = threadIdx.x;
        for (int i = t; i < NB; i += 256) h[i] = 0;
        __syncthreads();
        int base = j * CHUNK;
        #pragma unroll
        for (int k = 0; k < CHUNK / 256; k++) {
            int e = base + t + k * 256;
            if (e < N_EDGES) atomicAdd(&h[rows[e] >> BUCKET_SHIFT], 1);
        }
        __syncthreads();
        for (int i = t; i < NB; i += 256) gpartial[j * NB + i] = h[i];
    }
}

// ---------------------------------------------------------------------------
// Bucket scan (1 block): totals = sum_j gpartial[j][b]; exclusive scan ->
// bucket_base (392 entries) + bcursor seed; rowptr[N] = E.
// ---------------------------------------------------------------------------
__global__ __launch_bounds__(512) void bucket_scan_kernel(
    const int* __restrict__ gpartial, int* __restrict__ bucket_base,
    int* __restrict__ bcursor, int* __restrict__ rowptr) {
    __shared__ int s[512];
    int t = threadIdx.x;
    int total = 0;
    if (t < NB) {
        #pragma unroll 4
        for (int j = 0; j < NCHUNK; j++) total += gpartial[j * NB + t];
    }
    s[t] = total;
    __syncthreads();
    #pragma unroll
    for (int off = 1; off < 512; off <<= 1) {
        int u = (t >= off) ? s[t - off] : 0;
        __syncthreads();
        s[t] += u;
        __syncthreads();
    }
    if (t < NB) {
        int excl = s[t] - total;
        bucket_base[t] = excl;
        bcursor[t] = excl;
    }
    if (t == 0) { bucket_base[NB] = N_EDGES; rowptr[N_NODES] = N_EDGES; }
}

// ---------------------------------------------------------------------------
// Bucketize: compact each 4096-edge chunk into per-bucket LDS runs (offsets
// from gpartial, no re-histogram), reserve global ranges via one atomic per
// bucket, copy runs out coalesced.
// Edge payload: word0 = col(16) | lrow(7) | bucket(9), word1 = fp32 val.
// ---------------------------------------------------------------------------
__global__ __launch_bounds__(512) void bucketize_kernel(
    const int* __restrict__ rows, const int* __restrict__ cols,
    const float* __restrict__ vals, const int* __restrict__ gpartial,
    int* __restrict__ bcursor, int2* __restrict__ edges) {
    __shared__ int ob[512];            // exclusive chunk-local bucket offsets
    __shared__ int c[NB];              // placement cursors
    __shared__ int g[NB];              // reserved global bases
    __shared__ int2 buf[CHUNK];        // 32 KB
    int t = threadIdx.x;
    int j = blockIdx.x;
    int base = j * CHUNK;
    int M = N_EDGES - base; if (M > CHUNK) M = CHUNK;
    int cnt = (t < NB) ? gpartial[j * NB + t] : 0;
    ob[t] = cnt;
    __syncthreads();
    #pragma unroll
    for (int off = 1; off < 512; off <<= 1) {
        int u = (t >= off) ? ob[t - off] : 0;
        __syncthreads();
        ob[t] += u;
        __syncthreads();
    }
    ob[t] -= cnt;  // exclusive (own slot only)
    if (t < NB) {
        c[t] = 0;
        g[t] = (cnt > 0) ? atomicAdd(&bcursor[t], cnt) : 0;
    }
    __syncthreads();
    #pragma unroll
    for (int k = 0; k < CHUNK / 512; k++) {
        int e = base + t + k * 512;
        if (e < N_EDGES) {
            int r = rows[e];
            int bb = r >> BUCKET_SHIFT;
            int p = ob[bb] + atomicAdd(&c[bb], 1);
            buf[p] = make_int2(cols[e] | ((r & 127) << 16) | (bb << 23),
                               __float_as_int(vals[e]));
        }
    }
    __syncthreads();
    for (int i = t; i < M; i += 512) {
        int2 e = buf[i];
        int bb = (int)((uint32)e.x >> 23);
        edges[g[bb] + (i - ob[bb])] = e;
    }
}

// ---------------------------------------------------------------------------
// Bucket sort: per-bucket LDS counting sort by local row, in place; ALSO
// emits rowptr for its 128 rows (base + exclusive prefix). Global-scratch
// fallback if a bucket exceeds CAP_B (statistically impossible, kept safe).
// ---------------------------------------------------------------------------
__global__ __launch_bounds__(256) void bucket_sort_kernel(
    const int* __restrict__ bucket_base, int2* __restrict__ edges,
    int2* __restrict__ scratch, int* __restrict__ rowptr) {
    __shared__ int2 buf[CAP_B];   // 20.5 KB
    __shared__ int2 buf2[CAP_B];  // 20.5 KB
    __shared__ int h[128], o[128], c[128];
    int b = blockIdx.x, t = threadIdx.x;
    int base = bucket_base[b];
    int cnt = bucket_base[b + 1] - base;
    bool fits = (cnt <= CAP_B);
    if (t < 128) h[t] = 0;
    __syncthreads();
    for (int i = t; i < cnt; i += 256) {
        int2 e = edges[base + i];
        if (fits) buf[i] = e; else scratch[base + i] = e;
        atomicAdd(&h[(e.x >> 16) & 127], 1);
    }
    __syncthreads();
    int valh = (t < 128) ? h[t] : 0;
    #pragma unroll
    for (int off = 1; off < 128; off <<= 1) {
        int u = (t >= off && t < 128) ? h[t - off] : 0;
        __syncthreads();
        if (t < 128) h[t] += u;
        __syncthreads();
    }
    if (t < 128) {
        o[t] = h[t] - valh;
        c[t] = 0;
        int i = (b << BUCKET_SHIFT) + t;
        if (i < N_NODES) rowptr[i] = base + h[t] - valh;
    }
    __syncthreads();
    for (int i = t; i < cnt; i += 256) {
        int2 e = fits ? buf[i] : scratch[base + i];
        int lr = (e.x >> 16) & 127;
        int p = o[lr] + atomicAdd(&c[lr], 1);
        if (fits) buf2[p] = e; else edges[base + p] = e;
    }
    __syncthreads();
    if (fits)
        for (int i = t; i < cnt; i += 256) edges[base + i] = buf2[i];
}

// ---------------------------------------------------------------------------
// CSR spmm (bf16 feat, D=128). One wave/row, lane owns 2 dims, 8-wide MLP.
// col is the low 16 bits of the packed edge word.
// ---------------------------------------------------------------------------
template <bool OUT_F32>
__global__ __launch_bounds__(256) void spmm_csr_bf16(
    const uint32* __restrict__ feat, const int* __restrict__ rowptr,
    const int2* __restrict__ edges, const float* __restrict__ bias,
    void* __restrict__ outv) {
    int row = (blockIdx.x * blockDim.x + threadIdx.x) >> 6;
    int lane = threadIdx.x & 63;
    if (row >= N_NODES) return;
    int start = rowptr[row], end = rowptr[row + 1];
    float ax0 = 0.f, ay0 = 0.f, ax1 = 0.f, ay1 = 0.f;
    float ax2 = 0.f, ay2 = 0.f, ax3 = 0.f, ay3 = 0.f;
    for (int base = start; base < end; base += 64) {
        int n = end - base; if (n > 64) n = 64;
        int2 ev = make_int2(0, 0);
        if (lane < n) ev = edges[base + lane];
        int c = ev.x & 0xFFFF; float v = __int_as_float(ev.y);
        int j = 0;
        for (; j + 8 <= n; j += 8) {
            int c0 = __shfl(c, j, 64), c1 = __shfl(c, j + 1, 64);
            int c2 = __shfl(c, j + 2, 64), c3 = __shfl(c, j + 3, 64);
            int c4 = __shfl(c, j + 4, 64), c5 = __shfl(c, j + 5, 64);
            int c6 = __shfl(c, j + 6, 64), c7 = __shfl(c, j + 7, 64);
            float v0 = __shfl(v, j, 64), v1 = __shfl(v, j + 1, 64);
            float v2 = __shfl(v, j + 2, 64), v3 = __shfl(v, j + 3, 64);
            float v4 = __shfl(v, j + 4, 64), v5 = __shfl(v, j + 5, 64);
            float v6 = __shfl(v, j + 6, 64), v7 = __shfl(v, j + 7, 64);
            uint32 f0 = feat[(size_t)c0 * 64 + lane];
            uint32 f1 = feat[(size_t)c1 * 64 + lane];
            uint32 f2 = feat[(size_t)c2 * 64 + lane];
            uint32 f3 = feat[(size_t)c3 * 64 + lane];
            uint32 f4 = feat[(size_t)c4 * 64 + lane];
            uint32 f5 = feat[(size_t)c5 * 64 + lane];
            uint32 f6 = feat[(size_t)c6 * 64 + lane];
            uint32 f7 = feat[(size_t)c7 * 64 + lane];
            ax0 += v0 * bf_lo(f0); ay0 += v0 * bf_hi(f0);
            ax1 += v1 * bf_lo(f1); ay1 += v1 * bf_hi(f1);
            ax2 += v2 * bf_lo(f2); ay2 += v2 * bf_hi(f2);
            ax3 += v3 * bf_lo(f3); ay3 += v3 * bf_hi(f3);
            ax0 += v4 * bf_lo(f4); ay0 += v4 * bf_hi(f4);
            ax1 += v5 * bf_lo(f5); ay1 += v5 * bf_hi(f5);
            ax2 += v6 * bf_lo(f6); ay2 += v6 * bf_hi(f6);
            ax3 += v7 * bf_lo(f7); ay3 += v7 * bf_hi(f7);
        }
        for (; j + 4 <= n; j += 4) {
            int c0 = __shfl(c, j, 64), c1 = __shfl(c, j + 1, 64);
            int c2 = __shfl(c, j + 2, 64), c3 = __shfl(c, j + 3, 64);
            float v0 = __shfl(v, j, 64), v1 = __shfl(v, j + 1, 64);
            float v2 = __shfl(v, j + 2, 64), v3 = __shfl(v, j + 3, 64);
            uint32 f0 = feat[(size_t)c0 * 64 + lane];
            uint32 f1 = feat[(size_t)c1 * 64 + lane];
            uint32 f2 = feat[(size_t)c2 * 64 + lane];
            uint32 f3 = feat[(size_t)c3 * 64 + lane];
            ax0 += v0 * bf_lo(f0); ay0 += v0 * bf_hi(f0);
            ax1 += v1 * bf_lo(f1); ay1 += v1 * bf_hi(f1);
            ax2 += v2 * bf_lo(f2); ay2 += v2 * bf_hi(f2);
            ax3 += v3 * bf_lo(f3); ay3 += v3 * bf_hi(f3);
        }
        for (; j < n; j++) {
            int c0 = __shfl(c, j, 64);
            float v0 = __shfl(v, j, 64);
            uint32 f0 = feat[(size_t)c0 * 64 + lane];
            ax0 += v0 * bf_lo(f0); ay0 += v0 * bf_hi(f0);
        }
    }
    float ax = (ax0 + ax1) + (ax2 + ax3);
    float ay = (ay0 + ay1) + (ay2 + ay3);
    if (OUT_F32) {
        float2 b = ((const float2*)bias)[lane];
        ((float2*)outv)[(size_t)row * 64 + lane] = make_float2(ax + b.x, ay + b.y);
    } else {
        ((uint32*)outv)[(size_t)row * 64 + lane] =
            (uint32)f2bf(ax) | ((uint32)f2bf(ay) << 16);
    }
}

// ---------------------------------------------------------------------------
// Fused MFMA GEMM (weight-stationary): hw = relu(agg1 @ W1 + b1) @ W2.
// ---------------------------------------------------------------------------
__global__ __launch_bounds__(256, 3) void gemm_fused(
    const uint32* __restrict__ agg1, const ushort16* __restrict__ W1t,
    const ushort16* __restrict__ W2t, const float* __restrict__ b1,
    ushort16* __restrict__ hw, int nrows) {
    __shared__ ushort16 a_s[64 * 136];
    __shared__ ushort16 h_s[64 * 264];
    const int tx = threadIdx.x;
    const int wave = tx >> 6, lane = tx & 63;
    const int quad = lane >> 4, l16 = lane & 15;
    const int row0 = blockIdx.x * 64;

    short8 bfr1[4][4];  // [ct][kk]
    #pragma unroll
    for (int ct = 0; ct < 4; ct++)
        #pragma unroll
        for (int kk = 0; kk < 4; kk++)
            bfr1[ct][kk] = *(const short8*)
                &W1t[(wave * 64 + ct * 16 + l16) * 128 + kk * 32 + quad * 8];

    #pragma unroll
    for (int i = 0; i < 16; i++) {
        int idx = tx + i * 256;
        int r = idx >> 6, c = idx & 63;
        uint32 v = 0;
        if (row0 + r < nrows) v = agg1[(size_t)(row0 + r) * 64 + c];
        *(uint32*)&a_s[r * 136 + c * 2] = v;
    }
    __syncthreads();

    floatx4 acc1[4][4];  // [rs][ct]
    #pragma unroll
    for (int rs = 0; rs < 4; rs++)
        #pragma unroll
        for (int ct = 0; ct < 4; ct++)
            #pragma unroll
            for (int j = 0; j < 4; j++) acc1[rs][ct][j] = 0.f;
    #pragma unroll
    for (int kk = 0; kk < 4; kk++) {
        #pragma unroll
        for (int rs = 0; rs < 4; rs++) {
            short8 af = *(const short8*)&a_s[(rs * 16 + l16) * 136 + kk * 32 + quad * 8];
            #pragma unroll
            for (int ct = 0; ct < 4; ct++)
                acc1[rs][ct] = __builtin_amdgcn_mfma_f32_16x16x32_bf16(
                    af, bfr1[ct][kk], acc1[rs][ct], 0, 0, 0);
        }
    }
    float bv[4];
    #pragma unroll
    for (int ct = 0; ct < 4; ct++) bv[ct] = b1[wave * 64 + ct * 16 + l16];
    #pragma unroll
    for (int rs = 0; rs < 4; rs++)
        #pragma unroll
        for (int ct = 0; ct < 4; ct++)
            #pragma unroll
            for (int reg = 0; reg < 4; reg++) {
                float v = acc1[rs][ct][reg] + bv[ct];
                v = v > 0.f ? v : 0.f;
                h_s[(rs * 16 + quad * 4 + reg) * 264 + wave * 64 + ct * 16 + l16] = f2bf(v);
            }

    short8 bfr2[2][8];  // [ct][kk]
    #pragma unroll
    for (int ct = 0; ct < 2; ct++)
        #pragma unroll
        for (int kk = 0; kk < 8; kk++)
            bfr2[ct][kk] = *(const short8*)
                &W2t[(wave * 32 + ct * 16 + l16) * 256 + kk * 32 + quad * 8];
    __syncthreads();

    floatx4 acc2[4][2];
    #pragma unroll
    for (int rs = 0; rs < 4; rs++)
        #pragma unroll
        for (int ct = 0; ct < 2; ct++)
            #pragma unroll
            for (int j = 0; j < 4; j++) acc2[rs][ct][j] = 0.f;
    #pragma unroll
    for (int kk = 0; kk < 8; kk++) {
        #pragma unroll
        for (int rs = 0; rs < 4; rs++) {
            short8 af = *(const short8*)&h_s[(rs * 16 + l16) * 264 + kk * 32 + quad * 8];
            #pragma unroll
            for (int ct = 0; ct < 2; ct++)
                acc2[rs][ct] = __builtin_amdgcn_mfma_f32_16x16x32_bf16(
                    af, bfr2[ct][kk], acc2[rs][ct], 0, 0, 0);
        }
    }
    #pragma unroll
    for (int rs = 0; rs < 4; rs++)
        #pragma unroll
        for (int ct = 0; ct < 2; ct++)
            #pragma unroll
            for (int reg = 0; reg < 4; reg++) {
                int row = row0 + rs * 16 + quad * 4 + reg;
                if (row < nrows)
                    hw[(size_t)row * 128 + wave * 32 + ct * 16 + l16] =
                        f2bf(acc2[rs][ct][reg]);
            }
}

extern "C" void kernel_launch(void* const* d_in, const int* in_sizes, int n_in,
                              void* d_out, int out_size, void* d_ws, size_t ws_size,
                              hipStream_t stream) {
    const float* x = (const float*)d_in[0];
    const float* adj_vals = (const float*)d_in[1];
    const int* adj_row = (const int*)d_in[2];
    const int* adj_col = (const int*)d_in[3];
    const float* W1 = (const float*)d_in[4];
    const float* b1 = (const float*)d_in[5];
    const float* W2 = (const float*)d_in[6];
    const float* b2 = (const float*)d_in[7];
    float* out = (float*)d_out;

    // Workspace layout (~52 MB):
    char* ws = (char*)d_ws;
    uint32*   xb       = (uint32*)  (ws + 0);            // 12.8 MB (bf16 x-norm)
    uint32*   agg1     = (uint32*)  (ws + 12800000);     // 12.8 MB (bf16)
    ushort16* hw       = (ushort16*)(ws + 25600000);     // 12.8 MB (bf16)
    int2*     edges    = (int2*)    (ws + 38400000);     //  6.4 MB
    int2*     scratch  = (int2*)    (ws + 44800000);     //  6.4 MB (fallback only)
    int*      gpartial = (int*)     (ws + 51200000);     //  306 KB
    int*      rowptr   = (int*)     (ws + 51513344);     //  200 KB
    int*      bbase    = (int*)     (ws + 51714048);     //  1.6 KB
    int*      bcursor  = (int*)     (ws + 51716096);     //  1.6 KB
    ushort16* W1t      = (ushort16*)(ws + 51718144);     //   64 KB
    ushort16* W2t      = (ushort16*)(ws + 51783680);     //   64 KB

    // 1. prep: x-hat bf16 + transposed bf16 weights + per-chunk bucket hists
    hipLaunchKernelGGL(prep_kernel, dim3(NORM_BLOCKS + CONV_BLOCKS + NCHUNK),
                       dim3(256), 0, stream, x, xb, W1, W2, W1t, W2t,
                       adj_row, gpartial);

    // 2. bucket bases (scan of 391 totals)
    hipLaunchKernelGGL(bucket_scan_kernel, dim3(1), dim3(512),
                       0, stream, gpartial, bbase, bcursor, rowptr);

    // 3. bucketize (coalesced) + per-bucket sort (emits rowptr)
    hipLaunchKernelGGL(bucketize_kernel, dim3(NCHUNK), dim3(512),
                       0, stream, adj_row, adj_col, adj_vals, gpartial, bcursor, edges);
    hipLaunchKernelGGL(bucket_sort_kernel, dim3(NB), dim3(256),
                       0, stream, bbase, edges, scratch, rowptr);

    // 4. agg1 = A @ x-hat
    hipLaunchKernelGGL((spmm_csr_bf16<false>), dim3((N_NODES * 64 + 255) / 256), dim3(256),
                       0, stream, xb, rowptr, edges, (const float*)nullptr, (void*)agg1);

    // 5. hw = relu(agg1 @ W1 + b1) @ W2   [fused MFMA, weight-stationary]
    hipLaunchKernelGGL(gemm_fused, dim3((N_NODES + 63) / 64), dim3(256),
                       0, stream, agg1, W1t, W2t, b1, hw, N_NODES);

    // 6. out = A @ hw + b2
    hipLaunchKernelGGL((spmm_csr_bf16<true>), dim3((N_NODES * 64 + 255) / 256), dim3(256),
                       0, stream, (const uint32*)hw, rowptr, edges, b2, (void*)out);
}

// Round 10
// 223.492 us; speedup vs baseline: 13.0143x; 1.0012x over previous
//
#include <hip/hip_runtime.h>

// Problem constants (fixed by the reference).
#define N_NODES 50000
#define N_EDGES 800000
#define X_DIM 128
#define H_DIM 256
#define Y_DIM 128

typedef unsigned int uint32;
typedef unsigned short ushort16;
typedef __attribute__((ext_vector_type(8))) short short8;
typedef __attribute__((ext_vector_type(4))) float floatx4;

// bf16 helpers (round-to-nearest-even)
__device__ inline ushort16 f2bf(float f) {
    uint32 u = __float_as_uint(f);
    return (ushort16)((u + 0x7FFFu + ((u >> 16) & 1u)) >> 16);
}
__device__ inline float bf_lo(uint32 u) { return __uint_as_float(u << 16); }
__device__ inline float bf_hi(uint32 u) { return __uint_as_float(u & 0xFFFF0000u); }

// Bucket geometry: 391 buckets of 128 rows; 196 chunks of 4096 edges.
#define BUCKET_SHIFT 7
#define NB 391              // ceil(50000/128)
#define CHUNK 4096
#define NCHUNK 196          // ceil(800000/4096)
#define CAP_B 2560          // LDS capacity per bucket (mean 2046)

#define NORM_BLOCKS 12500   // N_NODES*64/256
#define CONV_BLOCKS 256     // 65536/256

// ---------------------------------------------------------------------------
// Prep (fused): row-normalize x -> bf16; transpose-convert W1,W2 to bf16;
// per-chunk bucket histograms -> gpartial[chunk][bucket] (no global atomics).
// ---------------------------------------------------------------------------
__global__ __launch_bounds__(256) void prep_kernel(
    const float* __restrict__ x, uint32* __restrict__ xb,
    const float* __restrict__ W1, const float* __restrict__ W2,
    ushort16* __restrict__ W1t, ushort16* __restrict__ W2t,
    const int* __restrict__ rows, int* __restrict__ gpartial) {
    int b = blockIdx.x;
    if (b < NORM_BLOCKS) {
        int row = (b * 256 + threadIdx.x) >> 6;  // exact: 12500*4 = 50000 rows
        int lane = threadIdx.x & 63;
        float2 v = ((const float2*)x)[(size_t)row * 64 + lane];
        float s = v.x + v.y;
        #pragma unroll
        for (int off = 32; off > 0; off >>= 1) s += __shfl_xor(s, off, 64);
        float inv = 1.0f / (s + 1e-4f);
        uint32 lo = (uint32)f2bf(v.x * inv);
        uint32 hi = (uint32)f2bf(v.y * inv);
        xb[(size_t)row * 64 + lane] = lo | (hi << 16);
    } else if (b < NORM_BLOCKS + CONV_BLOCKS) {
        int t = (b - NORM_BLOCKS) * 256 + threadIdx.x;  // 0..65535
        if (t < X_DIM * H_DIM) {
            int n = t >> 7, k = t & 127;           // W1t[n][k] = W1[k][n]
            W1t[t] = f2bf(W1[k * H_DIM + n]);
        } else {
            int u = t - X_DIM * H_DIM;
            int y = u >> 8, k = u & 255;           // W2t[y][k] = W2[k][y]
            W2t[u] = f2bf(W2[k * Y_DIM + y]);
        }
    } else {
        __shared__ int h[NB];
        int j = b - NORM_BLOCKS - CONV_BLOCKS;     // chunk id 0..195
        int t = threadIdx.x;
        for (int i = t; i < NB; i += 256) h[i] = 0;
        __syncthreads();
        int base = j * CHUNK;
        #pragma unroll
        for (int k = 0; k < CHUNK / 256; k++) {
            int e = base + t + k * 256;
            if (e < N_EDGES) atomicAdd(&h[rows[e] >> BUCKET_SHIFT], 1);
        }
        __syncthreads();
        for (int i = t; i < NB; i += 256) gpartial[j * NB + i] = h[i];
    }
}

// ---------------------------------------------------------------------------
// Bucket scan (1 block): totals = sum_j gpartial[j][b]; exclusive scan ->
// bucket_base (392 entries) + bcursor seed; rowptr[N] = E.
// ---------------------------------------------------------------------------
__global__ __launch_bounds__(512) void bucket_scan_kernel(
    const int* __restrict__ gpartial, int* __restrict__ bucket_base,
    int* __restrict__ bcursor, int* __restrict__ rowptr) {
    __shared__ int s[512];
    int t = threadIdx.x;
    int total = 0;
    if (t < NB) {
        #pragma unroll 4
        for (int j = 0; j < NCHUNK; j++) total += gpartial[j * NB + t];
    }
    s[t] = total;
    __syncthreads();
    #pragma unroll
    for (int off = 1; off < 512; off <<= 1) {
        int u = (t >= off) ? s[t - off] : 0;
        __syncthreads();
        s[t] += u;
        __syncthreads();
    }
    if (t < NB) {
        int excl = s[t] - total;
        bucket_base[t] = excl;
        bcursor[t] = excl;
    }
    if (t == 0) { bucket_base[NB] = N_EDGES; rowptr[N_NODES] = N_EDGES; }
}

// ---------------------------------------------------------------------------
// Bucketize: compact each 4096-edge chunk into per-bucket LDS runs (offsets
// from gpartial), reserve global ranges via one atomic per bucket, copy out.
// Edge payload: word0 = col(16) | lrow(7) | bucket(9), word1 = fp32 val.
// ---------------------------------------------------------------------------
__global__ __launch_bounds__(512) void bucketize_kernel(
    const int* __restrict__ rows, const int* __restrict__ cols,
    const float* __restrict__ vals, const int* __restrict__ gpartial,
    int* __restrict__ bcursor, int2* __restrict__ edges) {
    __shared__ int ob[512];            // exclusive chunk-local bucket offsets
    __shared__ int c[NB];              // placement cursors
    __shared__ int g[NB];              // reserved global bases
    __shared__ int2 buf[CHUNK];        // 32 KB
    int t = threadIdx.x;
    int j = blockIdx.x;
    int base = j * CHUNK;
    int M = N_EDGES - base; if (M > CHUNK) M = CHUNK;
    int cnt = (t < NB) ? gpartial[j * NB + t] : 0;
    ob[t] = cnt;
    __syncthreads();
    #pragma unroll
    for (int off = 1; off < 512; off <<= 1) {
        int u = (t >= off) ? ob[t - off] : 0;
        __syncthreads();
        ob[t] += u;
        __syncthreads();
    }
    ob[t] -= cnt;  // exclusive (own slot only)
    if (t < NB) {
        c[t] = 0;
        g[t] = (cnt > 0) ? atomicAdd(&bcursor[t], cnt) : 0;
    }
    __syncthreads();
    #pragma unroll
    for (int k = 0; k < CHUNK / 512; k++) {
        int e = base + t + k * 512;
        if (e < N_EDGES) {
            int r = rows[e];
            int bb = r >> BUCKET_SHIFT;
            int p = ob[bb] + atomicAdd(&c[bb], 1);
            buf[p] = make_int2(cols[e] | ((r & 127) << 16) | (bb << 23),
                               __float_as_int(vals[e]));
        }
    }
    __syncthreads();
    for (int i = t; i < M; i += 512) {
        int2 e = buf[i];
        int bb = (int)((uint32)e.x >> 23);
        edges[g[bb] + (i - ob[bb])] = e;
    }
}

// ---------------------------------------------------------------------------
// Bucket sort: per-bucket LDS counting sort by local row, in place; ALSO
// emits rowptr for its 128 rows. Global-scratch fallback if bucket > CAP_B.
// ---------------------------------------------------------------------------
__global__ __launch_bounds__(256) void bucket_sort_kernel(
    const int* __restrict__ bucket_base, int2* __restrict__ edges,
    int2* __restrict__ scratch, int* __restrict__ rowptr) {
    __shared__ int2 buf[CAP_B];   // 20.5 KB
    __shared__ int2 buf2[CAP_B];  // 20.5 KB
    __shared__ int h[128], o[128], c[128];
    int b = blockIdx.x, t = threadIdx.x;
    int base = bucket_base[b];
    int cnt = bucket_base[b + 1] - base;
    bool fits = (cnt <= CAP_B);
    if (t < 128) h[t] = 0;
    __syncthreads();
    for (int i = t; i < cnt; i += 256) {
        int2 e = edges[base + i];
        if (fits) buf[i] = e; else scratch[base + i] = e;
        atomicAdd(&h[(e.x >> 16) & 127], 1);
    }
    __syncthreads();
    int valh = (t < 128) ? h[t] : 0;
    #pragma unroll
    for (int off = 1; off < 128; off <<= 1) {
        int u = (t >= off && t < 128) ? h[t - off] : 0;
        __syncthreads();
        if (t < 128) h[t] += u;
        __syncthreads();
    }
    if (t < 128) {
        o[t] = h[t] - valh;
        c[t] = 0;
        int i = (b << BUCKET_SHIFT) + t;
        if (i < N_NODES) rowptr[i] = base + h[t] - valh;
    }
    __syncthreads();
    for (int i = t; i < cnt; i += 256) {
        int2 e = fits ? buf[i] : scratch[base + i];
        int lr = (e.x >> 16) & 127;
        int p = o[lr] + atomicAdd(&c[lr], 1);
        if (fits) buf2[p] = e; else edges[base + p] = e;
    }
    __syncthreads();
    if (fits)
        for (int i = t; i < cnt; i += 256) edges[base + i] = buf2[i];
}

// ---------------------------------------------------------------------------
// Shared spmm row accumulator: lane owns dims {2*lane, 2*lane+1}. 8-wide MLP,
// padded to 8 (lanes >= n hold zeroed edges -> v=0, harmless feat[0] gather).
// ---------------------------------------------------------------------------
__device__ inline void spmm_row(const uint32* __restrict__ feat,
                                const int2* __restrict__ edges,
                                int start, int end, int lane,
                                float& AX, float& AY) {
    float ax0 = 0.f, ay0 = 0.f, ax1 = 0.f, ay1 = 0.f;
    float ax2 = 0.f, ay2 = 0.f, ax3 = 0.f, ay3 = 0.f;
    for (int base = start; base < end; base += 64) {
        int n = end - base; if (n > 64) n = 64;
        int2 ev = make_int2(0, 0);
        if (lane < n) ev = edges[base + lane];
        int c = ev.x & 0xFFFF; float v = __int_as_float(ev.y);
        int n8 = (n + 7) & ~7;
        for (int j = 0; j < n8; j += 8) {
            int c0 = __shfl(c, j, 64), c1 = __shfl(c, j + 1, 64);
            int c2 = __shfl(c, j + 2, 64), c3 = __shfl(c, j + 3, 64);
            int c4 = __shfl(c, j + 4, 64), c5 = __shfl(c, j + 5, 64);
            int c6 = __shfl(c, j + 6, 64), c7 = __shfl(c, j + 7, 64);
            float v0 = __shfl(v, j, 64), v1 = __shfl(v, j + 1, 64);
            float v2 = __shfl(v, j + 2, 64), v3 = __shfl(v, j + 3, 64);
            float v4 = __shfl(v, j + 4, 64), v5 = __shfl(v, j + 5, 64);
            float v6 = __shfl(v, j + 6, 64), v7 = __shfl(v, j + 7, 64);
            uint32 f0 = feat[(size_t)c0 * 64 + lane];
            uint32 f1 = feat[(size_t)c1 * 64 + lane];
            uint32 f2 = feat[(size_t)c2 * 64 + lane];
            uint32 f3 = feat[(size_t)c3 * 64 + lane];
            uint32 f4 = feat[(size_t)c4 * 64 + lane];
            uint32 f5 = feat[(size_t)c5 * 64 + lane];
            uint32 f6 = feat[(size_t)c6 * 64 + lane];
            uint32 f7 = feat[(size_t)c7 * 64 + lane];
            ax0 += v0 * bf_lo(f0); ay0 += v0 * bf_hi(f0);
            ax1 += v1 * bf_lo(f1); ay1 += v1 * bf_hi(f1);
            ax2 += v2 * bf_lo(f2); ay2 += v2 * bf_hi(f2);
            ax3 += v3 * bf_lo(f3); ay3 += v3 * bf_hi(f3);
            ax0 += v4 * bf_lo(f4); ay0 += v4 * bf_hi(f4);
            ax1 += v5 * bf_lo(f5); ay1 += v5 * bf_hi(f5);
            ax2 += v6 * bf_lo(f6); ay2 += v6 * bf_hi(f6);
            ax3 += v7 * bf_lo(f7); ay3 += v7 * bf_hi(f7);
        }
    }
    AX = (ax0 + ax1) + (ax2 + ax3);
    AY = (ay0 + ay1) + (ay2 + ay3);
}

// ---------------------------------------------------------------------------
// Fused SPMM + double GEMM: per 64-row tile (512 thr, 8 waves):
//   phase 0: each wave gathers 8 rows of agg1 = A @ x-hat straight into the
//            LDS A-tile (packed bf16, identical rounding to the old agg1).
//   phase 1: h = relu(A @ W1 + b1) via MFMA, wave owns 32 h-cols,
//            B-fragments preloaded once (weight-stationary). C->A round trip
//            through h_s.
//   phase 2: hw = h @ W2, wave owns 16 hw-cols. Written bf16.
// LDS 51.2 KB -> 3 blocks/CU if VGPR <= 85 (bound caps at 128 -> >= 2).
// ---------------------------------------------------------------------------
__global__ __launch_bounds__(512, 4) void spmm_gemm_fused(
    const uint32* __restrict__ xb, const int* __restrict__ rowptr,
    const int2* __restrict__ edges, const ushort16* __restrict__ W1t,
    const ushort16* __restrict__ W2t, const float* __restrict__ b1,
    ushort16* __restrict__ hw) {
    __shared__ ushort16 a_s[64 * 136];  // 17.4 KB
    __shared__ ushort16 h_s[64 * 264];  // 33.8 KB
    const int tx = threadIdx.x;
    const int wave = tx >> 6, lane = tx & 63;
    const int quad = lane >> 4, l16 = lane & 15;
    const int row0 = blockIdx.x * 64;

    // Preload stage-1 B fragments: wave owns h-cols [wave*32, wave*32+32)
    short8 bfr1[2][4];  // [ct][kk]
    #pragma unroll
    for (int ct = 0; ct < 2; ct++)
        #pragma unroll
        for (int kk = 0; kk < 4; kk++)
            bfr1[ct][kk] = *(const short8*)
                &W1t[(wave * 32 + ct * 16 + l16) * 128 + kk * 32 + quad * 8];

    // Phase 0: gather 8 rows per wave directly into the A-tile
    #pragma unroll
    for (int i = 0; i < 8; i++) {
        int r = wave * 8 + i;
        int row = row0 + r;
        float ax = 0.f, ay = 0.f;
        if (row < N_NODES) {
            int start = rowptr[row], end = rowptr[row + 1];
            spmm_row(xb, edges, start, end, lane, ax, ay);
        }
        *(uint32*)&a_s[r * 136 + lane * 2] =
            (uint32)f2bf(ax) | ((uint32)f2bf(ay) << 16);
    }
    __syncthreads();

    // Phase 1: h = relu(A @ W1 + b1)
    floatx4 acc1[4][2];  // [rs][ct]
    #pragma unroll
    for (int rs = 0; rs < 4; rs++)
        #pragma unroll
        for (int ct = 0; ct < 2; ct++)
            #pragma unroll
            for (int j = 0; j < 4; j++) acc1[rs][ct][j] = 0.f;
    #pragma unroll
    for (int kk = 0; kk < 4; kk++) {
        #pragma unroll
        for (int rs = 0; rs < 4; rs++) {
            short8 af = *(const short8*)&a_s[(rs * 16 + l16) * 136 + kk * 32 + quad * 8];
            #pragma unroll
            for (int ct = 0; ct < 2; ct++)
                acc1[rs][ct] = __builtin_amdgcn_mfma_f32_16x16x32_bf16(
                    af, bfr1[ct][kk], acc1[rs][ct], 0, 0, 0);
        }
    }
    float bv[2];
    #pragma unroll
    for (int ct = 0; ct < 2; ct++) bv[ct] = b1[wave * 32 + ct * 16 + l16];
    #pragma unroll
    for (int rs = 0; rs < 4; rs++)
        #pragma unroll
        for (int ct = 0; ct < 2; ct++)
            #pragma unroll
            for (int reg = 0; reg < 4; reg++) {
                float v = acc1[rs][ct][reg] + bv[ct];
                v = v > 0.f ? v : 0.f;
                h_s[(rs * 16 + quad * 4 + reg) * 264 + wave * 32 + ct * 16 + l16] = f2bf(v);
            }

    // Preload stage-2 B fragments: wave owns hw-cols [wave*16, wave*16+16)
    short8 bfr2[8];
    #pragma unroll
    for (int kk = 0; kk < 8; kk++)
        bfr2[kk] = *(const short8*)
            &W2t[(wave * 16 + l16) * 256 + kk * 32 + quad * 8];
    __syncthreads();

    // Phase 2: hw = h @ W2
    floatx4 acc2[4];
    #pragma unroll
    for (int rs = 0; rs < 4; rs++)
        #pragma unroll
        for (int j = 0; j < 4; j++) acc2[rs][j] = 0.f;
    #pragma unroll
    for (int kk = 0; kk < 8; kk++) {
        #pragma unroll
        for (int rs = 0; rs < 4; rs++) {
            short8 af = *(const short8*)&h_s[(rs * 16 + l16) * 264 + kk * 32 + quad * 8];
            acc2[rs] = __builtin_amdgcn_mfma_f32_16x16x32_bf16(
                af, bfr2[kk], acc2[rs], 0, 0, 0);
        }
    }
    #pragma unroll
    for (int rs = 0; rs < 4; rs++)
        #pragma unroll
        for (int reg = 0; reg < 4; reg++) {
            int row = row0 + rs * 16 + quad * 4 + reg;
            if (row < N_NODES)
                hw[(size_t)row * 128 + wave * 16 + l16] = f2bf(acc2[rs][reg]);
        }
}

// ---------------------------------------------------------------------------
// Final spmm: out = A @ hw + b2 (fp32 out). One wave/row.
// ---------------------------------------------------------------------------
__global__ __launch_bounds__(256) void spmm_out_kernel(
    const uint32* __restrict__ feat, const int* __restrict__ rowptr,
    const int2* __restrict__ edges, const float* __restrict__ bias,
    float* __restrict__ out) {
    int row = (blockIdx.x * blockDim.x + threadIdx.x) >> 6;
    int lane = threadIdx.x & 63;
    if (row >= N_NODES) return;
    float ax, ay;
    spmm_row(feat, edges, rowptr[row], rowptr[row + 1], lane, ax, ay);
    float2 b = ((const float2*)bias)[lane];
    ((float2*)out)[(size_t)row * 64 + lane] = make_float2(ax + b.x, ay + b.y);
}

extern "C" void kernel_launch(void* const* d_in, const int* in_sizes, int n_in,
                              void* d_out, int out_size, void* d_ws, size_t ws_size,
                              hipStream_t stream) {
    const float* x = (const float*)d_in[0];
    const float* adj_vals = (const float*)d_in[1];
    const int* adj_row = (const int*)d_in[2];
    const int* adj_col = (const int*)d_in[3];
    const float* W1 = (const float*)d_in[4];
    const float* b1 = (const float*)d_in[5];
    const float* W2 = (const float*)d_in[6];
    const float* b2 = (const float*)d_in[7];
    float* out = (float*)d_out;

    // Workspace layout (~39 MB):
    char* ws = (char*)d_ws;
    uint32*   xb       = (uint32*)  (ws + 0);            // 12.8 MB (bf16 x-norm)
    ushort16* hw       = (ushort16*)(ws + 12800000);     // 12.8 MB (bf16)
    int2*     edges    = (int2*)    (ws + 25600000);     //  6.4 MB
    int2*     scratch  = (int2*)    (ws + 32000000);     //  6.4 MB (fallback only)
    int*      gpartial = (int*)     (ws + 38400000);     //  306 KB
    int*      rowptr   = (int*)     (ws + 38713344);     //  200 KB
    int*      bbase    = (int*)     (ws + 38914048);     //  1.6 KB
    int*      bcursor  = (int*)     (ws + 38916096);     //  1.6 KB
    ushort16* W1t      = (ushort16*)(ws + 38918144);     //   64 KB
    ushort16* W2t      = (ushort16*)(ws + 38983680);     //   64 KB

    // 1. prep: x-hat bf16 + transposed bf16 weights + per-chunk bucket hists
    hipLaunchKernelGGL(prep_kernel, dim3(NORM_BLOCKS + CONV_BLOCKS + NCHUNK),
                       dim3(256), 0, stream, x, xb, W1, W2, W1t, W2t,
                       adj_row, gpartial);

    // 2. bucket bases (scan of 391 totals)
    hipLaunchKernelGGL(bucket_scan_kernel, dim3(1), dim3(512),
                       0, stream, gpartial, bbase, bcursor, rowptr);

    // 3. bucketize (coalesced) + per-bucket sort (emits rowptr)
    hipLaunchKernelGGL(bucketize_kernel, dim3(NCHUNK), dim3(512),
                       0, stream, adj_row, adj_col, adj_vals, gpartial, bcursor, edges);
    hipLaunchKernelGGL(bucket_sort_kernel, dim3(NB), dim3(256),
                       0, stream, bbase, edges, scratch, rowptr);

    // 4. hw = relu((A @ x-hat) @ W1 + b1) @ W2   [fused spmm + MFMA GEMMs]
    hipLaunchKernelGGL(spmm_gemm_fused, dim3((N_NODES + 63) / 64), dim3(512),
                       0, stream, xb, rowptr, edges, W1t, W2t, b1, hw);

    // 5. out = A @ hw + b2
    hipLaunchKernelGGL(spmm_out_kernel, dim3((N_NODES * 64 + 255) / 256), dim3(256),
                       0, stream, (const uint32*)hw, rowptr, edges, b2, out);
}

// Round 11
// 211.991 us; speedup vs baseline: 13.7203x; 1.0543x over previous
//
#include <hip/hip_runtime.h>

// Problem constants (fixed by the reference).
#define N_NODES 50000
#define N_EDGES 800000
#define X_DIM 128
#define H_DIM 256
#define Y_DIM 128

typedef unsigned int uint32;
typedef unsigned short ushort16;
typedef __attribute__((ext_vector_type(8))) short short8;
typedef __attribute__((ext_vector_type(4))) float floatx4;

// bf16 helpers (round-to-nearest-even)
__device__ inline ushort16 f2bf(float f) {
    uint32 u = __float_as_uint(f);
    return (ushort16)((u + 0x7FFFu + ((u >> 16) & 1u)) >> 16);
}
__device__ inline float bf_lo(uint32 u) { return __uint_as_float(u << 16); }
__device__ inline float bf_hi(uint32 u) { return __uint_as_float(u & 0xFFFF0000u); }

// Bucket geometry: 391 buckets of 128 rows; 196 chunks of 4096 edges.
#define BUCKET_SHIFT 7
#define NB 391              // ceil(50000/128)
#define CHUNK 4096
#define NCHUNK 196          // ceil(800000/4096)
#define CAP_B 2560          // LDS capacity per bucket (mean 2046)

#define NORM_BLOCKS 12500   // N_NODES*64/256
#define CONV_BLOCKS 256     // 65536/256

// ---------------------------------------------------------------------------
// Prep (fused): row-normalize x -> bf16; transpose-convert W1,W2 to bf16;
// per-chunk bucket histograms -> gpartial[chunk][bucket] (no global atomics).
// ---------------------------------------------------------------------------
__global__ __launch_bounds__(256) void prep_kernel(
    const float* __restrict__ x, uint32* __restrict__ xb,
    const float* __restrict__ W1, const float* __restrict__ W2,
    ushort16* __restrict__ W1t, ushort16* __restrict__ W2t,
    const int* __restrict__ rows, int* __restrict__ gpartial) {
    int b = blockIdx.x;
    if (b < NORM_BLOCKS) {
        int row = (b * 256 + threadIdx.x) >> 6;  // exact: 12500*4 = 50000 rows
        int lane = threadIdx.x & 63;
        float2 v = ((const float2*)x)[(size_t)row * 64 + lane];
        float s = v.x + v.y;
        #pragma unroll
        for (int off = 32; off > 0; off >>= 1) s += __shfl_xor(s, off, 64);
        float inv = 1.0f / (s + 1e-4f);
        uint32 lo = (uint32)f2bf(v.x * inv);
        uint32 hi = (uint32)f2bf(v.y * inv);
        xb[(size_t)row * 64 + lane] = lo | (hi << 16);
    } else if (b < NORM_BLOCKS + CONV_BLOCKS) {
        int t = (b - NORM_BLOCKS) * 256 + threadIdx.x;  // 0..65535
        if (t < X_DIM * H_DIM) {
            int n = t >> 7, k = t & 127;           // W1t[n][k] = W1[k][n]
            W1t[t] = f2bf(W1[k * H_DIM + n]);
        } else {
            int u = t - X_DIM * H_DIM;
            int y = u >> 8, k = u & 255;           // W2t[y][k] = W2[k][y]
            W2t[u] = f2bf(W2[k * Y_DIM + y]);
        }
    } else {
        __shared__ int h[NB];
        int j = b - NORM_BLOCKS - CONV_BLOCKS;     // chunk id 0..195
        int t = threadIdx.x;
        for (int i = t; i < NB; i += 256) h[i] = 0;
        __syncthreads();
        int base = j * CHUNK;
        #pragma unroll
        for (int k = 0; k < CHUNK / 256; k++) {
            int e = base + t + k * 256;
            if (e < N_EDGES) atomicAdd(&h[rows[e] >> BUCKET_SHIFT], 1);
        }
        __syncthreads();
        for (int i = t; i < NB; i += 256) gpartial[j * NB + i] = h[i];
    }
}

// ---------------------------------------------------------------------------
// Bucket scan (1 block): totals = sum_j gpartial[j][b]; exclusive scan ->
// bucket_base (392 entries) + bcursor seed; rowptr[N] = E.
// ---------------------------------------------------------------------------
__global__ __launch_bounds__(512) void bucket_scan_kernel(
    const int* __restrict__ gpartial, int* __restrict__ bucket_base,
    int* __restrict__ bcursor, int* __restrict__ rowptr) {
    __shared__ int s[512];
    int t = threadIdx.x;
    int total = 0;
    if (t < NB) {
        #pragma unroll 4
        for (int j = 0; j < NCHUNK; j++) total += gpartial[j * NB + t];
    }
    s[t] = total;
    __syncthreads();
    #pragma unroll
    for (int off = 1; off < 512; off <<= 1) {
        int u = (t >= off) ? s[t - off] : 0;
        __syncthreads();
        s[t] += u;
        __syncthreads();
    }
    if (t < NB) {
        int excl = s[t] - total;
        bucket_base[t] = excl;
        bcursor[t] = excl;
    }
    if (t == 0) { bucket_base[NB] = N_EDGES; rowptr[N_NODES] = N_EDGES; }
}

// ---------------------------------------------------------------------------
// Bucketize: compact each 4096-edge chunk into per-bucket LDS runs (offsets
// from gpartial), reserve global ranges via one atomic per bucket, copy out.
// Edge payload: word0 = col(16) | lrow(7) | bucket(9), word1 = fp32 val.
// ---------------------------------------------------------------------------
__global__ __launch_bounds__(512) void bucketize_kernel(
    const int* __restrict__ rows, const int* __restrict__ cols,
    const float* __restrict__ vals, const int* __restrict__ gpartial,
    int* __restrict__ bcursor, int2* __restrict__ edges) {
    __shared__ int ob[512];            // exclusive chunk-local bucket offsets
    __shared__ int c[NB];              // placement cursors
    __shared__ int g[NB];              // reserved global bases
    __shared__ int2 buf[CHUNK];        // 32 KB
    int t = threadIdx.x;
    int j = blockIdx.x;
    int base = j * CHUNK;
    int M = N_EDGES - base; if (M > CHUNK) M = CHUNK;
    int cnt = (t < NB) ? gpartial[j * NB + t] : 0;
    ob[t] = cnt;
    __syncthreads();
    #pragma unroll
    for (int off = 1; off < 512; off <<= 1) {
        int u = (t >= off) ? ob[t - off] : 0;
        __syncthreads();
        ob[t] += u;
        __syncthreads();
    }
    ob[t] -= cnt;  // exclusive (own slot only)
    if (t < NB) {
        c[t] = 0;
        g[t] = (cnt > 0) ? atomicAdd(&bcursor[t], cnt) : 0;
    }
    __syncthreads();
    #pragma unroll
    for (int k = 0; k < CHUNK / 512; k++) {
        int e = base + t + k * 512;
        if (e < N_EDGES) {
            int r = rows[e];
            int bb = r >> BUCKET_SHIFT;
            int p = ob[bb] + atomicAdd(&c[bb], 1);
            buf[p] = make_int2(cols[e] | ((r & 127) << 16) | (bb << 23),
                               __float_as_int(vals[e]));
        }
    }
    __syncthreads();
    for (int i = t; i < M; i += 512) {
        int2 e = buf[i];
        int bb = (int)((uint32)e.x >> 23);
        edges[g[bb] + (i - ob[bb])] = e;
    }
}

// ---------------------------------------------------------------------------
// Bucket sort: per-bucket LDS counting sort by local row, in place; ALSO
// emits rowptr for its 128 rows. Global-scratch fallback if bucket > CAP_B.
// ---------------------------------------------------------------------------
__global__ __launch_bounds__(256) void bucket_sort_kernel(
    const int* __restrict__ bucket_base, int2* __restrict__ edges,
    int2* __restrict__ scratch, int* __restrict__ rowptr) {
    __shared__ int2 buf[CAP_B];   // 20.5 KB
    __shared__ int2 buf2[CAP_B];  // 20.5 KB
    __shared__ int h[128], o[128], c[128];
    int b = blockIdx.x, t = threadIdx.x;
    int base = bucket_base[b];
    int cnt = bucket_base[b + 1] - base;
    bool fits = (cnt <= CAP_B);
    if (t < 128) h[t] = 0;
    __syncthreads();
    for (int i = t; i < cnt; i += 256) {
        int2 e = edges[base + i];
        if (fits) buf[i] = e; else scratch[base + i] = e;
        atomicAdd(&h[(e.x >> 16) & 127], 1);
    }
    __syncthreads();
    int valh = (t < 128) ? h[t] : 0;
    #pragma unroll
    for (int off = 1; off < 128; off <<= 1) {
        int u = (t >= off && t < 128) ? h[t - off] : 0;
        __syncthreads();
        if (t < 128) h[t] += u;
        __syncthreads();
    }
    if (t < 128) {
        o[t] = h[t] - valh;
        c[t] = 0;
        int i = (b << BUCKET_SHIFT) + t;
        if (i < N_NODES) rowptr[i] = base + h[t] - valh;
    }
    __syncthreads();
    for (int i = t; i < cnt; i += 256) {
        int2 e = fits ? buf[i] : scratch[base + i];
        int lr = (e.x >> 16) & 127;
        int p = o[lr] + atomicAdd(&c[lr], 1);
        if (fits) buf2[p] = e; else edges[base + p] = e;
    }
    __syncthreads();
    if (fits)
        for (int i = t; i < cnt; i += 256) edges[base + i] = buf2[i];
}

// ---------------------------------------------------------------------------
// Dual-row spmm accumulator: lanes 0-31 process row A (lane owns dims
// hl*4..hl*4+3 via uint2 = 4 bf16), lanes 32-63 row B. 8-wide edge unroll:
// 8 independent 8B gathers in flight serving two rows at once.
// start/end are per-lane (uniform within each half).
// ---------------------------------------------------------------------------
__device__ inline void spmm_row2(const uint2* __restrict__ feat2,
                                 const int2* __restrict__ edges,
                                 int start, int end, int lane,
                                 float& A0, float& A1, float& A2, float& A3) {
    const int hl = lane & 31;
    const int bsrc = lane & 32;   // shfl source base for my half
    float x0 = 0.f, x1 = 0.f, x2 = 0.f, x3 = 0.f;
    int cur = start;
    while (__any(cur < end)) {
        int n = end - cur;
        n = n < 0 ? 0 : (n > 32 ? 32 : n);
        int2 ev = make_int2(0, 0);
        if (hl < n) ev = edges[cur + hl];
        int c = ev.x & 0xFFFF;
        float v = __int_as_float(ev.y);
        int na = __shfl(n, 0, 64), nb = __shfl(n, 32, 64);
        int nm = na > nb ? na : nb;
        int jm = (nm + 7) & ~7;
        for (int j = 0; j < jm; j += 8) {
            int c0 = __shfl(c, bsrc + j, 64),     c1 = __shfl(c, bsrc + j + 1, 64);
            int c2 = __shfl(c, bsrc + j + 2, 64), c3 = __shfl(c, bsrc + j + 3, 64);
            int c4 = __shfl(c, bsrc + j + 4, 64), c5 = __shfl(c, bsrc + j + 5, 64);
            int c6 = __shfl(c, bsrc + j + 6, 64), c7 = __shfl(c, bsrc + j + 7, 64);
            float v0 = __shfl(v, bsrc + j, 64),     v1 = __shfl(v, bsrc + j + 1, 64);
            float v2 = __shfl(v, bsrc + j + 2, 64), v3 = __shfl(v, bsrc + j + 3, 64);
            float v4 = __shfl(v, bsrc + j + 4, 64), v5 = __shfl(v, bsrc + j + 5, 64);
            float v6 = __shfl(v, bsrc + j + 6, 64), v7 = __shfl(v, bsrc + j + 7, 64);
            uint2 f0 = feat2[(size_t)c0 * 32 + hl];
            uint2 f1 = feat2[(size_t)c1 * 32 + hl];
            uint2 f2 = feat2[(size_t)c2 * 32 + hl];
            uint2 f3 = feat2[(size_t)c3 * 32 + hl];
            uint2 f4 = feat2[(size_t)c4 * 32 + hl];
            uint2 f5 = feat2[(size_t)c5 * 32 + hl];
            uint2 f6 = feat2[(size_t)c6 * 32 + hl];
            uint2 f7 = feat2[(size_t)c7 * 32 + hl];
            x0 += v0 * bf_lo(f0.x); x1 += v0 * bf_hi(f0.x);
            x2 += v0 * bf_lo(f0.y); x3 += v0 * bf_hi(f0.y);
            x0 += v1 * bf_lo(f1.x); x1 += v1 * bf_hi(f1.x);
            x2 += v1 * bf_lo(f1.y); x3 += v1 * bf_hi(f1.y);
            x0 += v2 * bf_lo(f2.x); x1 += v2 * bf_hi(f2.x);
            x2 += v2 * bf_lo(f2.y); x3 += v2 * bf_hi(f2.y);
            x0 += v3 * bf_lo(f3.x); x1 += v3 * bf_hi(f3.x);
            x2 += v3 * bf_lo(f3.y); x3 += v3 * bf_hi(f3.y);
            x0 += v4 * bf_lo(f4.x); x1 += v4 * bf_hi(f4.x);
            x2 += v4 * bf_lo(f4.y); x3 += v4 * bf_hi(f4.y);
            x0 += v5 * bf_lo(f5.x); x1 += v5 * bf_hi(f5.x);
            x2 += v5 * bf_lo(f5.y); x3 += v5 * bf_hi(f5.y);
            x0 += v6 * bf_lo(f6.x); x1 += v6 * bf_hi(f6.x);
            x2 += v6 * bf_lo(f6.y); x3 += v6 * bf_hi(f6.y);
            x0 += v7 * bf_lo(f7.x); x1 += v7 * bf_hi(f7.x);
            x2 += v7 * bf_lo(f7.y); x3 += v7 * bf_hi(f7.y);
        }
        cur += n;
    }
    A0 = x0; A1 = x1; A2 = x2; A3 = x3;
}

// ---------------------------------------------------------------------------
// Fused SPMM + double GEMM per 64-row tile (512 thr, 8 waves):
//   phase 0: each wave gathers 8 rows (4 passes x 2 rows, dual-row) of
//            agg1 = A @ x-hat straight into the LDS A-tile (packed bf16).
//   phase 1: h = relu(A @ W1 + b1) via MFMA, wave owns 32 h-cols
//            (B-fragments loaded AFTER phase 0 to free gather registers).
//   phase 2: hw = h @ W2, wave owns 16 hw-cols. Written bf16.
// LDS 51.2 KB -> 3 blocks/CU (24 waves) while VGPR <= 64.
// ---------------------------------------------------------------------------
__global__ __launch_bounds__(512, 4) void spmm_gemm_fused(
    const uint32* __restrict__ xb, const int* __restrict__ rowptr,
    const int2* __restrict__ edges, const ushort16* __restrict__ W1t,
    const ushort16* __restrict__ W2t, const float* __restrict__ b1,
    ushort16* __restrict__ hw) {
    __shared__ ushort16 a_s[64 * 136];  // 17.4 KB
    __shared__ ushort16 h_s[64 * 264];  // 33.8 KB
    const int tx = threadIdx.x;
    const int wave = tx >> 6, lane = tx & 63;
    const int quad = lane >> 4, l16 = lane & 15;
    const int half = lane >> 5, hl = lane & 31;
    const int row0 = blockIdx.x * 64;
    const uint2* xb2 = (const uint2*)xb;

    // Phase 0: gather 8 rows per wave (2 at a time) into the A-tile
    for (int i = 0; i < 4; i++) {
        int r = wave * 8 + i * 2 + half;
        int row = row0 + r;
        int s = 0, e = 0;
        if (row < N_NODES) { s = rowptr[row]; e = rowptr[row + 1]; }
        float a0, a1, a2, a3;
        spmm_row2(xb2, edges, s, e, lane, a0, a1, a2, a3);
        uint32 lo = (uint32)f2bf(a0) | ((uint32)f2bf(a1) << 16);
        uint32 hi = (uint32)f2bf(a2) | ((uint32)f2bf(a3) << 16);
        *(uint2*)&a_s[r * 136 + hl * 4] = make_uint2(lo, hi);
    }

    // Preload stage-1 B fragments AFTER the gather (register pressure):
    // wave owns h-cols [wave*32, wave*32+32)
    short8 bfr1[2][4];  // [ct][kk]
    #pragma unroll
    for (int ct = 0; ct < 2; ct++)
        #pragma unroll
        for (int kk = 0; kk < 4; kk++)
            bfr1[ct][kk] = *(const short8*)
                &W1t[(wave * 32 + ct * 16 + l16) * 128 + kk * 32 + quad * 8];
    __syncthreads();

    // Phase 1: h = relu(A @ W1 + b1)
    floatx4 acc1[4][2];  // [rs][ct]
    #pragma unroll
    for (int rs = 0; rs < 4; rs++)
        #pragma unroll
        for (int ct = 0; ct < 2; ct++)
            #pragma unroll
            for (int j = 0; j < 4; j++) acc1[rs][ct][j] = 0.f;
    #pragma unroll
    for (int kk = 0; kk < 4; kk++) {
        #pragma unroll
        for (int rs = 0; rs < 4; rs++) {
            short8 af = *(const short8*)&a_s[(rs * 16 + l16) * 136 + kk * 32 + quad * 8];
            #pragma unroll
            for (int ct = 0; ct < 2; ct++)
                acc1[rs][ct] = __builtin_amdgcn_mfma_f32_16x16x32_bf16(
                    af, bfr1[ct][kk], acc1[rs][ct], 0, 0, 0);
        }
    }
    float bv[2];
    #pragma unroll
    for (int ct = 0; ct < 2; ct++) bv[ct] = b1[wave * 32 + ct * 16 + l16];
    #pragma unroll
    for (int rs = 0; rs < 4; rs++)
        #pragma unroll
        for (int ct = 0; ct < 2; ct++)
            #pragma unroll
            for (int reg = 0; reg < 4; reg++) {
                float v = acc1[rs][ct][reg] + bv[ct];
                v = v > 0.f ? v : 0.f;
                h_s[(rs * 16 + quad * 4 + reg) * 264 + wave * 32 + ct * 16 + l16] = f2bf(v);
            }

    // Preload stage-2 B fragments: wave owns hw-cols [wave*16, wave*16+16)
    short8 bfr2[8];
    #pragma unroll
    for (int kk = 0; kk < 8; kk++)
        bfr2[kk] = *(const short8*)
            &W2t[(wave * 16 + l16) * 256 + kk * 32 + quad * 8];
    __syncthreads();

    // Phase 2: hw = h @ W2
    floatx4 acc2[4];
    #pragma unroll
    for (int rs = 0; rs < 4; rs++)
        #pragma unroll
        for (int j = 0; j < 4; j++) acc2[rs][j] = 0.f;
    #pragma unroll
    for (int kk = 0; kk < 8; kk++) {
        #pragma unroll
        for (int rs = 0; rs < 4; rs++) {
            short8 af = *(const short8*)&h_s[(rs * 16 + l16) * 264 + kk * 32 + quad * 8];
            acc2[rs] = __builtin_amdgcn_mfma_f32_16x16x32_bf16(
                af, bfr2[kk], acc2[rs], 0, 0, 0);
        }
    }
    #pragma unroll
    for (int rs = 0; rs < 4; rs++)
        #pragma unroll
        for (int reg = 0; reg < 4; reg++) {
            int row = row0 + rs * 16 + quad * 4 + reg;
            if (row < N_NODES)
                hw[(size_t)row * 128 + wave * 16 + l16] = f2bf(acc2[rs][reg]);
        }
}

// ---------------------------------------------------------------------------
// Final spmm: out = A @ hw + b2 (fp32 out). One wave per 2 rows (dual-row).
// Grid exact: 6250 blocks x 4 waves x 2 rows = 50000.
// ---------------------------------------------------------------------------
__global__ __launch_bounds__(256) void spmm_out_kernel(
    const uint32* __restrict__ feat, const int* __restrict__ rowptr,
    const int2* __restrict__ edges, const float* __restrict__ bias,
    float* __restrict__ out) {
    int w = (blockIdx.x * blockDim.x + threadIdx.x) >> 6;
    int lane = threadIdx.x & 63;
    int half = lane >> 5, hl = lane & 31;
    int row = w * 2 + half;  // always < N_NODES (exact grid)
    int s = rowptr[row], e = rowptr[row + 1];
    float a0, a1, a2, a3;
    spmm_row2((const uint2*)feat, edges, s, e, lane, a0, a1, a2, a3);
    float4 b = ((const float4*)bias)[hl];
    ((float4*)out)[(size_t)row * 32 + hl] =
        make_float4(a0 + b.x, a1 + b.y, a2 + b.z, a3 + b.w);
}

extern "C" void kernel_launch(void* const* d_in, const int* in_sizes, int n_in,
                              void* d_out, int out_size, void* d_ws, size_t ws_size,
                              hipStream_t stream) {
    const float* x = (const float*)d_in[0];
    const float* adj_vals = (const float*)d_in[1];
    const int* adj_row = (const int*)d_in[2];
    const int* adj_col = (const int*)d_in[3];
    const float* W1 = (const float*)d_in[4];
    const float* b1 = (const float*)d_in[5];
    const float* W2 = (const float*)d_in[6];
    const float* b2 = (const float*)d_in[7];
    float* out = (float*)d_out;

    // Workspace layout (~39 MB):
    char* ws = (char*)d_ws;
    uint32*   xb       = (uint32*)  (ws + 0);            // 12.8 MB (bf16 x-norm)
    ushort16* hw       = (ushort16*)(ws + 12800000);     // 12.8 MB (bf16)
    int2*     edges    = (int2*)    (ws + 25600000);     //  6.4 MB
    int2*     scratch  = (int2*)    (ws + 32000000);     //  6.4 MB (fallback only)
    int*      gpartial = (int*)     (ws + 38400000);     //  306 KB
    int*      rowptr   = (int*)     (ws + 38713344);     //  200 KB
    int*      bbase    = (int*)     (ws + 38914048);     //  1.6 KB
    int*      bcursor  = (int*)     (ws + 38916096);     //  1.6 KB
    ushort16* W1t      = (ushort16*)(ws + 38918144);     //   64 KB
    ushort16* W2t      = (ushort16*)(ws + 38983680);     //   64 KB

    // 1. prep: x-hat bf16 + transposed bf16 weights + per-chunk bucket hists
    hipLaunchKernelGGL(prep_kernel, dim3(NORM_BLOCKS + CONV_BLOCKS + NCHUNK),
                       dim3(256), 0, stream, x, xb, W1, W2, W1t, W2t,
                       adj_row, gpartial);

    // 2. bucket bases (scan of 391 totals)
    hipLaunchKernelGGL(bucket_scan_kernel, dim3(1), dim3(512),
                       0, stream, gpartial, bbase, bcursor, rowptr);

    // 3. bucketize (coalesced) + per-bucket sort (emits rowptr)
    hipLaunchKernelGGL(bucketize_kernel, dim3(NCHUNK), dim3(512),
                       0, stream, adj_row, adj_col, adj_vals, gpartial, bcursor, edges);
    hipLaunchKernelGGL(bucket_sort_kernel, dim3(NB), dim3(256),
                       0, stream, bbase, edges, scratch, rowptr);

    // 4. hw = relu((A @ x-hat) @ W1 + b1) @ W2   [fused spmm + MFMA GEMMs]
    hipLaunchKernelGGL(spmm_gemm_fused, dim3((N_NODES + 63) / 64), dim3(512),
                       0, stream, xb, rowptr, edges, W1t, W2t, b1, hw);

    // 5. out = A @ hw + b2
    hipLaunchKernelGGL(spmm_out_kernel, dim3(N_NODES / 8), dim3(256),
                       0, stream, (const uint32*)hw, rowptr, edges, b2, out);
}